// Round 1
// baseline (223.069 us; speedup 1.0000x reference)
//
#include <hip/hip_runtime.h>
#include <hip/hip_bf16.h>
#include <math.h>

// MultiScaleRetention: B=2,N=4,S=1024,H=512, HEADS=8, HEAD=64
// Pipeline:
//  P0 X->bf16 ; P1 WcatT (Q|K|V|G pre-transposed, 2048x512) ; P2 WoT ; P3 xpos tables
//  K1 proj GEMM (8192x512)@(512x2048) + xpos/silu epilogue -> Qb,Kb,Vb,Gb (bf16)
//  K2 retention + decay + groupnorm -> Yb (bf16)
//  K3 out GEMM A=(gate*Y) @ WoT -> d_out (fp32)

typedef __attribute__((ext_vector_type(8))) short bf16x8;
typedef __attribute__((ext_vector_type(4))) float f32x4;

#define MFMA16(a, b, c) __builtin_amdgcn_mfma_f32_16x16x32_bf16(a, b, c, 0, 0, 0)

__device__ __forceinline__ unsigned short f2bf(float f) {
  union { float f; unsigned u; } x; x.f = f;
  unsigned r = x.u + 0x7FFFu + ((x.u >> 16) & 1u);
  return (unsigned short)(r >> 16);
}
__device__ __forceinline__ float bf2f(unsigned short b) {
  union { unsigned u; float f; } x; x.u = ((unsigned)b) << 16;
  return x.f;
}

// ---------------- prep kernels ----------------

__global__ void k_x2bf(const float* __restrict__ X, unsigned short* __restrict__ Xb) {
  int idx = blockIdx.x * 256 + threadIdx.x;      // 4 elems each, n = 4194304
  float4 v = ((const float4*)X)[idx];
  ushort4 o;
  o.x = f2bf(v.x); o.y = f2bf(v.y); o.z = f2bf(v.z); o.w = f2bf(v.w);
  ((ushort4*)Xb)[idx] = o;
}

__global__ void k_wcat(const float* __restrict__ WQ, const float* __restrict__ WK,
                       const float* __restrict__ WV, const float* __restrict__ WG,
                       unsigned short* __restrict__ Wt) {
  int idx = blockIdx.x * 256 + threadIdx.x;      // n*512 + k, n in [0,2048)
  int n = idx >> 9, k = idx & 511;
  float w;
  if (n < 1536) {
    const float* W = (n < 512) ? WQ : (n < 1024 ? WK : WV);
    int c = n & 511; int g = c >> 6, d = c & 63;
    w = W[((size_t)g * 512 + k) * 64 + d];
  } else {
    w = WG[(size_t)k * 512 + (n - 1536)];
  }
  Wt[idx] = f2bf(w);
}

__global__ void k_wo(const float* __restrict__ WO, unsigned short* __restrict__ Wt) {
  int idx = blockIdx.x * 256 + threadIdx.x;      // n*512 + k
  int n = idx >> 9, k = idx & 511;
  Wt[idx] = f2bf(WO[(size_t)k * 512 + n]);
}

__global__ void k_tables(float* __restrict__ sinT, float* __restrict__ cosT,
                         float* __restrict__ scT, float* __restrict__ iscT) {
  int idx = blockIdx.x * 256 + threadIdx.x;      // s*64 + d, 1024x64
  int s = idx >> 6, d = idx & 63;
  int i = d >> 1;
  double invf = pow(10000.0, -(double)i / 32.0);
  double ang = (double)s * invf;
  sinT[idx] = (float)sin(ang);
  cosT[idx] = (float)cos(ang);
  double sv = (2.0 * i + 0.4 * 64.0) / (1.4 * 64.0);
  double sc = pow(sv, (double)s / 512.0);
  scT[idx] = (float)sc;
  iscT[idx] = (float)(1.0 / sc);
}

// ---------------- K1: projection GEMM + xpos/silu epilogue ----------------
// A = Xbf (8192x512 bf16 row-major), B = WcatT (2048x512, row n = out col, cols = k)
// grid (16 colblk, 64 rowblk), block 256 (4 waves, 2x2), tile 128x128, BK=32

__launch_bounds__(256)
__global__ void k_proj(const unsigned short* __restrict__ Xb, const unsigned short* __restrict__ Wt,
                       const float* __restrict__ sinT, const float* __restrict__ cosT,
                       const float* __restrict__ scT, const float* __restrict__ iscT,
                       unsigned short* __restrict__ Qb, unsigned short* __restrict__ Kb,
                       unsigned short* __restrict__ Vb, unsigned short* __restrict__ Gb) {
  __shared__ __attribute__((aligned(16))) unsigned short As[128][40];
  __shared__ __attribute__((aligned(16))) unsigned short Bs[128][40];
  const int tid = threadIdx.x, lane = tid & 63, wid = tid >> 6;
  const int wr = wid >> 1, wc = wid & 1;
  const int cb = blockIdx.x, rb = blockIdx.y;

  f32x4 acc[4][4] = {};
  const int kcol = (lane >> 4) * 8;

  for (int kt = 0; kt < 16; ++kt) {
    __syncthreads();
#pragma unroll
    for (int i = 0; i < 2; ++i) {
      int chunk = tid + 256 * i;            // 512 chunks of 8 = 128x32
      int r = chunk >> 2, c = (chunk & 3) * 8;
      *(bf16x8*)&As[r][c] = *(const bf16x8*)(Xb + (size_t)(rb * 128 + r) * 512 + kt * 32 + c);
      *(bf16x8*)&Bs[r][c] = *(const bf16x8*)(Wt + (size_t)(cb * 128 + r) * 512 + kt * 32 + c);
    }
    __syncthreads();
    bf16x8 a[4], b[4];
#pragma unroll
    for (int mi = 0; mi < 4; ++mi) a[mi] = *(const bf16x8*)&As[wr * 64 + mi * 16 + (lane & 15)][kcol];
#pragma unroll
    for (int ni = 0; ni < 4; ++ni) b[ni] = *(const bf16x8*)&Bs[wc * 64 + ni * 16 + (lane & 15)][kcol];
#pragma unroll
    for (int mi = 0; mi < 4; ++mi)
#pragma unroll
      for (int ni = 0; ni < 4; ++ni)
        acc[mi][ni] = MFMA16(a[mi], b[ni], acc[mi][ni]);
  }

  const int row0 = rb * 128 + wr * 64;
  const int colbase = cb * 128 + wc * 64;
  const int cls = cb >> 2;                  // 0=Q 1=K 2=V 3=gate (block-uniform)
#pragma unroll
  for (int mi = 0; mi < 4; ++mi) {
#pragma unroll
    for (int ni = 0; ni < 4; ++ni) {
      int colg = colbase + ni * 16 + (lane & 15);
      int d = colg & 63;
      int c = colg & 511;
#pragma unroll
      for (int r = 0; r < 4; ++r) {
        int row = row0 + mi * 16 + (lane >> 4) * 4 + r;
        float v = acc[mi][ni][r];
        if (cls == 0) {
          float p = __shfl_xor(v, 1);
          float rot = (d & 1) ? p : -p;     // rot2: even d -> -x[d+1], odd d -> x[d-1]
          int s = row & 1023;
          float q = (v * cosT[s * 64 + d] + rot * sinT[s * 64 + d]) * scT[s * 64 + d];
          Qb[(size_t)row * 512 + c] = f2bf(q);
        } else if (cls == 1) {
          float p = __shfl_xor(v, 1);
          float rot = (d & 1) ? p : -p;
          int s = row & 1023;
          float kv = (v * cosT[s * 64 + d] + rot * sinT[s * 64 + d]) * iscT[s * 64 + d];
          Kb[(size_t)row * 512 + c] = f2bf(kv);
        } else if (cls == 2) {
          Vb[(size_t)row * 512 + c] = f2bf(v);
        } else {
          float gsig = v / (1.f + __expf(-v));   // silu
          Gb[(size_t)row * 512 + c] = f2bf(gsig);
        }
      }
    }
  }
}

// ---------------- K2: retention + decay + groupnorm ----------------
// grid (8 sblk, 8 head, 8 seq), block 256 (4 waves); BM=128 q-rows, TBLK=64 kv-rows

__launch_bounds__(256)
__global__ void k_ret(const unsigned short* __restrict__ Qb, const unsigned short* __restrict__ Kb,
                      const unsigned short* __restrict__ Vb,
                      const float* __restrict__ gnw, const float* __restrict__ gnb,
                      unsigned short* __restrict__ Yb) {
  __shared__ __attribute__((aligned(16))) unsigned short Qs[128][72];
  __shared__ __attribute__((aligned(16))) unsigned short Ks[64][72];
  __shared__ __attribute__((aligned(16))) unsigned short Vs[64][72];  // transposed [d][t], XOR-block swizzled
  __shared__ __attribute__((aligned(16))) unsigned short Ss[128][72];
  const int sblk = blockIdx.x, g = blockIdx.y, bn = blockIdx.z;
  const int tid = threadIdx.x, lane = tid & 63, w = tid >> 6;

  // decay gamma for this head
  const float lg0 = logf(1.f / 32.f), lg1 = logf(1.f / 512.f);
  const float gam = 1.f - expf(lg0 + g * (lg1 - lg0) / 7.f);
  const float l2g = log2f(gam);

  const int s0 = sblk * 128;
  const size_t seqbase = (size_t)bn * 1024;

  // stage Q tile 128x64
#pragma unroll
  for (int i = 0; i < 4; ++i) {
    int chunk = tid + 256 * i;
    int r = chunk >> 3, c = (chunk & 7) * 8;
    *(bf16x8*)&Qs[r][c] = *(const bf16x8*)(Qb + (seqbase + s0 + r) * 512 + g * 64 + c);
  }

  f32x4 accY[2][4] = {};
  const int kc = (lane >> 4) * 8;
  const int ntt = 2 * sblk + 2;

  for (int tt = 0; tt < ntt; ++tt) {
    const int t0 = tt * 64;
    __syncthreads();   // protect prev-iter LDS reads (also covers Qs staging on iter 0)
#pragma unroll
    for (int i = 0; i < 2; ++i) {
      int chunk = tid + 256 * i;
      int r = chunk >> 3, c = (chunk & 7) * 8;
      *(bf16x8*)&Ks[r][c] = *(const bf16x8*)(Kb + (seqbase + t0 + r) * 512 + g * 64 + c);
      bf16x8 v = *(const bf16x8*)(Vb + (seqbase + t0 + r) * 512 + g * 64 + c);
      int tswz = r ^ (c & 0x38);            // XOR-block swizzle: conflict-free scalar writes
#pragma unroll
      for (int j = 0; j < 8; ++j) Vs[c + j][tswz] = (unsigned short)v[j];
    }
    __syncthreads();

    // S = Q K^T  (wave w: rows w*32..w*32+31, t cols 0..63)
    f32x4 accS[2][4] = {};
#pragma unroll
    for (int ks = 0; ks < 2; ++ks) {
      bf16x8 af[2], bfr[4];
#pragma unroll
      for (int mi = 0; mi < 2; ++mi) af[mi] = *(const bf16x8*)&Qs[w * 32 + mi * 16 + (lane & 15)][ks * 32 + kc];
#pragma unroll
      for (int ni = 0; ni < 4; ++ni) bfr[ni] = *(const bf16x8*)&Ks[ni * 16 + (lane & 15)][ks * 32 + kc];
#pragma unroll
      for (int mi = 0; mi < 2; ++mi)
#pragma unroll
        for (int ni = 0; ni < 4; ++ni)
          accS[mi][ni] = MFMA16(af[mi], bfr[ni], accS[mi][ni]);
    }

    // decay + S -> bf16 in LDS (wave-private rows; no barrier needed)
#pragma unroll
    for (int mi = 0; mi < 2; ++mi)
#pragma unroll
      for (int ni = 0; ni < 4; ++ni)
#pragma unroll
        for (int r = 0; r < 4; ++r) {
          int srow = w * 32 + mi * 16 + (lane >> 4) * 4 + r;
          int tcol = ni * 16 + (lane & 15);
          int diff = (s0 + srow) - (t0 + tcol);
          float dv = (diff >= 0) ? exp2f((float)diff * l2g) : 0.f;
          Ss[srow][tcol] = f2bf(accS[mi][ni][r] * dv);
        }

    // Y += S V
#pragma unroll
    for (int ks = 0; ks < 2; ++ks) {
      bf16x8 af[2], bfr[4];
#pragma unroll
      for (int mi = 0; mi < 2; ++mi) af[mi] = *(const bf16x8*)&Ss[w * 32 + mi * 16 + (lane & 15)][ks * 32 + kc];
#pragma unroll
      for (int ni = 0; ni < 4; ++ni) {
        int d = ni * 16 + (lane & 15);
        int colb = (ks * 32 + kc) ^ (d & 0x38);   // undo swizzle (8-aligned block XOR)
        bfr[ni] = *(const bf16x8*)&Vs[d][colb];
      }
#pragma unroll
      for (int mi = 0; mi < 2; ++mi)
#pragma unroll
        for (int ni = 0; ni < 4; ++ni)
          accY[mi][ni] = MFMA16(af[mi], bfr[ni], accY[mi][ni]);
    }
  }

  // groupnorm over d=64 per row, then write Ycat (bf16)
#pragma unroll
  for (int mi = 0; mi < 2; ++mi)
#pragma unroll
    for (int r = 0; r < 4; ++r) {
      float sm = 0.f, sq = 0.f;
#pragma unroll
      for (int ni = 0; ni < 4; ++ni) { float v = accY[mi][ni][r]; sm += v; sq += v * v; }
#pragma unroll
      for (int off = 1; off < 16; off <<= 1) { sm += __shfl_xor(sm, off); sq += __shfl_xor(sq, off); }
      float mean = sm * (1.f / 64.f);
      float var = sq * (1.f / 64.f) - mean * mean;
      float rstd = rsqrtf(var + 1e-5f);
      int row = w * 32 + mi * 16 + (lane >> 4) * 4 + r;
      size_t grow = seqbase + s0 + row;
#pragma unroll
      for (int ni = 0; ni < 4; ++ni) {
        int d = ni * 16 + (lane & 15);
        float v = (accY[mi][ni][r] - mean) * rstd * gnw[g * 64 + d] + gnb[g * 64 + d];
        Yb[grow * 512 + g * 64 + d] = f2bf(v);
      }
    }
}

// ---------------- K3: output GEMM, A = silu(gate) * Ycat ----------------
// grid (4 colblk, 64 rowblk), tile 128x128, K=512

__launch_bounds__(256)
__global__ void k_out(const unsigned short* __restrict__ Gb, const unsigned short* __restrict__ Yb,
                      const unsigned short* __restrict__ Wt, float* __restrict__ out) {
  __shared__ __attribute__((aligned(16))) unsigned short As[128][40];
  __shared__ __attribute__((aligned(16))) unsigned short Bs[128][40];
  const int tid = threadIdx.x, lane = tid & 63, wid = tid >> 6;
  const int wr = wid >> 1, wc = wid & 1;
  const int cb = blockIdx.x, rb = blockIdx.y;

  f32x4 acc[4][4] = {};
  const int kcol = (lane >> 4) * 8;

  for (int kt = 0; kt < 16; ++kt) {
    __syncthreads();
#pragma unroll
    for (int i = 0; i < 2; ++i) {
      int chunk = tid + 256 * i;
      int r = chunk >> 2, c = (chunk & 3) * 8;
      size_t off = (size_t)(rb * 128 + r) * 512 + kt * 32 + c;
      bf16x8 gv = *(const bf16x8*)(Gb + off);
      bf16x8 yv = *(const bf16x8*)(Yb + off);
      bf16x8 p;
#pragma unroll
      for (int j = 0; j < 8; ++j)
        p[j] = (short)f2bf(bf2f((unsigned short)gv[j]) * bf2f((unsigned short)yv[j]));
      *(bf16x8*)&As[r][c] = p;
      *(bf16x8*)&Bs[r][c] = *(const bf16x8*)(Wt + (size_t)(cb * 128 + r) * 512 + kt * 32 + c);
    }
    __syncthreads();
    bf16x8 a[4], b[4];
#pragma unroll
    for (int mi = 0; mi < 4; ++mi) a[mi] = *(const bf16x8*)&As[wr * 64 + mi * 16 + (lane & 15)][kcol];
#pragma unroll
    for (int ni = 0; ni < 4; ++ni) b[ni] = *(const bf16x8*)&Bs[wc * 64 + ni * 16 + (lane & 15)][kcol];
#pragma unroll
    for (int mi = 0; mi < 4; ++mi)
#pragma unroll
      for (int ni = 0; ni < 4; ++ni)
        acc[mi][ni] = MFMA16(a[mi], b[ni], acc[mi][ni]);
  }

  const int row0 = rb * 128 + wr * 64;
  const int colbase = cb * 128 + wc * 64;
#pragma unroll
  for (int mi = 0; mi < 4; ++mi)
#pragma unroll
    for (int ni = 0; ni < 4; ++ni) {
      int col = colbase + ni * 16 + (lane & 15);
#pragma unroll
      for (int r = 0; r < 4; ++r) {
        int row = row0 + mi * 16 + (lane >> 4) * 4 + r;
        out[(size_t)row * 512 + col] = acc[mi][ni][r];
      }
    }
}

// ---------------- launch ----------------

extern "C" void kernel_launch(void* const* d_in, const int* in_sizes, int n_in,
                              void* d_out, int out_size, void* d_ws, size_t ws_size,
                              hipStream_t stream) {
  const float* X   = (const float*)d_in[0];
  const float* WQ  = (const float*)d_in[1];
  const float* WK  = (const float*)d_in[2];
  const float* WV  = (const float*)d_in[3];
  const float* WG  = (const float*)d_in[4];
  const float* WO  = (const float*)d_in[5];
  const float* gnw = (const float*)d_in[6];
  const float* gnb = (const float*)d_in[7];
  float* out = (float*)d_out;

  char* ws = (char*)d_ws;
  const size_t SZ_BUF = (size_t)8192 * 512 * 2;   // 8 MB bf16
  unsigned short* Xb   = (unsigned short*)(ws);
  unsigned short* Qb   = (unsigned short*)(ws + SZ_BUF);
  unsigned short* Kb   = (unsigned short*)(ws + 2 * SZ_BUF);
  unsigned short* Vb   = (unsigned short*)(ws + 3 * SZ_BUF);
  unsigned short* Gb   = (unsigned short*)(ws + 4 * SZ_BUF);
  unsigned short* Yb   = (unsigned short*)(ws + 5 * SZ_BUF);
  unsigned short* Wcat = (unsigned short*)(ws + 6 * SZ_BUF);            // 2 MB
  unsigned short* WoT  = (unsigned short*)(ws + 6 * SZ_BUF + 2097152);  // 0.5 MB
  float* sinT = (float*)(ws + 6 * SZ_BUF + 2097152 + 524288);
  float* cosT = sinT + 65536;
  float* scT  = cosT + 65536;
  float* iscT = scT + 65536;

  k_tables<<<256, 256, 0, stream>>>(sinT, cosT, scT, iscT);
  k_x2bf<<<4096, 256, 0, stream>>>(X, Xb);
  k_wcat<<<4096, 256, 0, stream>>>(WQ, WK, WV, WG, Wcat);
  k_wo<<<1024, 256, 0, stream>>>(WO, WoT);
  k_proj<<<dim3(16, 64), 256, 0, stream>>>(Xb, Wcat, sinT, cosT, scT, iscT, Qb, Kb, Vb, Gb);
  k_ret<<<dim3(8, 8, 8), 256, 0, stream>>>(Qb, Kb, Vb, gnw, gnb, Yb);
  k_out<<<dim3(4, 64), 256, 0, stream>>>(Gb, Yb, WoT, out);
}

// Round 2
// 208.616 us; speedup vs baseline: 1.0693x; 1.0693x over previous
//
#include <hip/hip_runtime.h>
#include <hip/hip_bf16.h>
#include <math.h>

// MultiScaleRetention: B=2,N=4,S=1024,H=512, HEADS=8, HEAD=64
//  K1 proj GEMM (8192x512)@(512x2048) + xpos/silu epilogue -> Qb,Kb,Vb,Gb (bf16)
//  K2 retention + decay + groupnorm + gate -> Ab (bf16)
//  K3 out GEMM Ab @ WoT -> d_out (fp32)
// Staging: global_load_lds width=16 with pre-swizzled source (m173/T2 pattern),
// LDS tiles [R][64] bf16, row stride 128B, read swizzle byte ^= (row&7)<<4.

typedef __attribute__((ext_vector_type(8))) short bf16x8;
typedef __attribute__((ext_vector_type(4))) float f32x4;

#define MFMA16(a, b, c) __builtin_amdgcn_mfma_f32_16x16x32_bf16(a, b, c, 0, 0, 0)

__device__ __forceinline__ unsigned short f2bf(float f) {
  union { float f; unsigned u; } x; x.f = f;
  unsigned r = x.u + 0x7FFFu + ((x.u >> 16) & 1u);
  return (unsigned short)(r >> 16);
}
__device__ __forceinline__ float bf2f(unsigned short b) {
  union { unsigned u; float f; } x; x.u = ((unsigned)b) << 16;
  return x.f;
}

// 1KB chunk = 8 rows x 128B of a [R][64]-bf16 LDS tile. LDS dest is linear
// (wave-uniform base + lane*16); global source column is pre-swizzled so that
// reads can use byte ^ ((row&7)<<4) and land conflict-free (2-way).
__device__ __forceinline__ void gload_chunk(const unsigned short* gtile, size_t gstride,
                                            unsigned short* lds, int chunk, int lane) {
  int r = (chunk << 3) + (lane >> 3);
  int colel = ((lane & 7) ^ (lane >> 3)) << 3;
  const unsigned short* gp = gtile + (size_t)r * gstride + colel;
  __builtin_amdgcn_global_load_lds(
      (const __attribute__((address_space(1))) unsigned int*)gp,
      (__attribute__((address_space(3))) unsigned int*)((char*)lds + (chunk << 10)),
      16, 0, 0);
}

// swizzled b128 fragment read from a [R][64] tile staged by gload_chunk
__device__ __forceinline__ bf16x8 frag64(const unsigned short* lds, int row, int colel) {
  return *(const bf16x8*)((const char*)lds + row * 128 + ((colel * 2) ^ ((row & 7) << 4)));
}

// ---------------- prep kernels ----------------

__global__ void k_x2bf(const float* __restrict__ X, unsigned short* __restrict__ Xb) {
  int idx = blockIdx.x * 256 + threadIdx.x;
  float4 v = ((const float4*)X)[idx];
  ushort4 o;
  o.x = f2bf(v.x); o.y = f2bf(v.y); o.z = f2bf(v.z); o.w = f2bf(v.w);
  ((ushort4*)Xb)[idx] = o;
}

__global__ void k_wcat(const float* __restrict__ WQ, const float* __restrict__ WK,
                       const float* __restrict__ WV, const float* __restrict__ WG,
                       unsigned short* __restrict__ Wt) {
  int idx = blockIdx.x * 256 + threadIdx.x;      // n*512 + k, n in [0,2048)
  int n = idx >> 9, k = idx & 511;
  float w;
  if (n < 1536) {
    const float* W = (n < 512) ? WQ : (n < 1024 ? WK : WV);
    int c = n & 511; int g = c >> 6, d = c & 63;
    w = W[((size_t)g * 512 + k) * 64 + d];
  } else {
    w = WG[(size_t)k * 512 + (n - 1536)];
  }
  Wt[idx] = f2bf(w);
}

__global__ void k_wo(const float* __restrict__ WO, unsigned short* __restrict__ Wt) {
  int idx = blockIdx.x * 256 + threadIdx.x;      // n*512 + k
  int n = idx >> 9, k = idx & 511;
  Wt[idx] = f2bf(WO[(size_t)k * 512 + n]);
}

__global__ void k_tables(float* __restrict__ sinT, float* __restrict__ cosT,
                         float* __restrict__ scT, float* __restrict__ iscT) {
  int idx = blockIdx.x * 256 + threadIdx.x;      // s*64 + d
  int s = idx >> 6, d = idx & 63;
  int i = d >> 1;
  double invf = pow(10000.0, -(double)i / 32.0);
  double ang = (double)s * invf;
  sinT[idx] = (float)sin(ang);
  cosT[idx] = (float)cos(ang);
  double sv = (2.0 * i + 0.4 * 64.0) / (1.4 * 64.0);
  double sc = pow(sv, (double)s / 512.0);
  scT[idx] = (float)sc;
  iscT[idx] = (float)(1.0 / sc);
}

// ---------------- K1: projection GEMM + xpos/silu epilogue ----------------
// tile 128x128, BK=64, 4 waves 2x2; grid (16 colblk, 64 rowblk)

__launch_bounds__(256)
__global__ void k_proj(const unsigned short* __restrict__ Xb, const unsigned short* __restrict__ Wt,
                       const float* __restrict__ sinT, const float* __restrict__ cosT,
                       const float* __restrict__ scT, const float* __restrict__ iscT,
                       unsigned short* __restrict__ Qb, unsigned short* __restrict__ Kb,
                       unsigned short* __restrict__ Vb, unsigned short* __restrict__ Gb) {
  __shared__ __attribute__((aligned(16))) unsigned short As[128 * 64];
  __shared__ __attribute__((aligned(16))) unsigned short Bs[128 * 64];
  const int tid = threadIdx.x, lane = tid & 63, wid = tid >> 6;
  const int wr = wid >> 1, wc = wid & 1;
  const int cb = blockIdx.x, rb = blockIdx.y;

  f32x4 acc[4][4] = {};
  const int kc = (lane >> 4) * 8;
  const unsigned short* Ag = Xb + (size_t)(rb * 128) * 512;
  const unsigned short* Bg = Wt + (size_t)(cb * 128) * 512;

  for (int kt = 0; kt < 8; ++kt) {
    __syncthreads();
#pragma unroll
    for (int i = 0; i < 4; ++i) {
      gload_chunk(Ag + kt * 64, 512, As, wid * 4 + i, lane);
      gload_chunk(Bg + kt * 64, 512, Bs, wid * 4 + i, lane);
    }
    __syncthreads();
#pragma unroll
    for (int ks = 0; ks < 2; ++ks) {
      bf16x8 a[4], b[4];
#pragma unroll
      for (int mi = 0; mi < 4; ++mi) a[mi] = frag64(As, wr * 64 + mi * 16 + (lane & 15), ks * 32 + kc);
#pragma unroll
      for (int ni = 0; ni < 4; ++ni) b[ni] = frag64(Bs, wc * 64 + ni * 16 + (lane & 15), ks * 32 + kc);
#pragma unroll
      for (int mi = 0; mi < 4; ++mi)
#pragma unroll
        for (int ni = 0; ni < 4; ++ni)
          acc[mi][ni] = MFMA16(a[mi], b[ni], acc[mi][ni]);
    }
  }

  const int row0 = rb * 128 + wr * 64;
  const int colbase = cb * 128 + wc * 64;
  const int cls = cb >> 2;                  // 0=Q 1=K 2=V 3=gate
#pragma unroll
  for (int mi = 0; mi < 4; ++mi) {
#pragma unroll
    for (int ni = 0; ni < 4; ++ni) {
      int colg = colbase + ni * 16 + (lane & 15);
      int d = colg & 63;
      int c = colg & 511;
#pragma unroll
      for (int r = 0; r < 4; ++r) {
        int row = row0 + mi * 16 + (lane >> 4) * 4 + r;
        float v = acc[mi][ni][r];
        if (cls == 0) {
          float p = __shfl_xor(v, 1);
          float rot = (d & 1) ? p : -p;
          int s = row & 1023;
          float q = (v * cosT[s * 64 + d] + rot * sinT[s * 64 + d]) * scT[s * 64 + d];
          Qb[(size_t)row * 512 + c] = f2bf(q);
        } else if (cls == 1) {
          float p = __shfl_xor(v, 1);
          float rot = (d & 1) ? p : -p;
          int s = row & 1023;
          float kv = (v * cosT[s * 64 + d] + rot * sinT[s * 64 + d]) * iscT[s * 64 + d];
          Kb[(size_t)row * 512 + c] = f2bf(kv);
        } else if (cls == 2) {
          Vb[(size_t)row * 512 + c] = f2bf(v);
        } else {
          float gsig = v / (1.f + __expf(-v));   // silu
          Gb[(size_t)row * 512 + c] = f2bf(gsig);
        }
      }
    }
  }
}

// ---------------- K2: retention + decay + groupnorm + gate ----------------
// grid (8 sblk, 8 head, 8 seq), 4 waves; 128 q-rows, 64 kv-rows per tile

__launch_bounds__(256)
__global__ void k_ret(const unsigned short* __restrict__ Qb, const unsigned short* __restrict__ Kb,
                      const unsigned short* __restrict__ Vb, const unsigned short* __restrict__ Gb,
                      const float* __restrict__ gnw, const float* __restrict__ gnb,
                      unsigned short* __restrict__ Ab) {
  __shared__ __attribute__((aligned(16))) unsigned short Qs[128 * 64];
  __shared__ __attribute__((aligned(16))) unsigned short Ks[64 * 64];
  __shared__ __attribute__((aligned(16))) unsigned short Vs[64][72];   // [d][t^..] transposed
  __shared__ __attribute__((aligned(16))) unsigned short Ss[128][72];
  const int sblk = blockIdx.x, g = blockIdx.y, bn = blockIdx.z;
  const int tid = threadIdx.x, lane = tid & 63, w = tid >> 6;

  const float lg0 = logf(1.f / 32.f), lg1 = logf(1.f / 512.f);
  const float gam = 1.f - expf(lg0 + g * (lg1 - lg0) / 7.f);
  const float l2g = log2f(gam);

  const int s0 = sblk * 128;
  const size_t seqbase = (size_t)bn * 1024;

  // stage Q tile (drains at first loop barrier)
  const unsigned short* Qg = Qb + (seqbase + s0) * 512 + g * 64;
#pragma unroll
  for (int i = 0; i < 4; ++i) gload_chunk(Qg, 512, Qs, w * 4 + i, lane);

  f32x4 accY[2][4] = {};
  const int kc = (lane >> 4) * 8;
  const int ntt = 2 * sblk + 2;

  // V staging mapping: thread -> 2 rows x 8 cols
  const int t0p = (tid >> 3) * 2;
  const int c0v = (tid & 7) * 8;

  for (int tt = 0; tt < ntt; ++tt) {
    const int t0 = tt * 64;
    __syncthreads();   // prev-iter reads done (and Q gload drained on tt=0)
    gload_chunk(Kb + (seqbase + t0) * 512 + g * 64, 512, Ks, w * 2 + 0, lane);
    gload_chunk(Kb + (seqbase + t0) * 512 + g * 64, 512, Ks, w * 2 + 1, lane);
    {
      bf16x8 v0 = *(const bf16x8*)(Vb + (seqbase + t0 + t0p) * 512 + g * 64 + c0v);
      bf16x8 v1 = *(const bf16x8*)(Vb + (seqbase + t0 + t0p + 1) * 512 + g * 64 + c0v);
#pragma unroll
      for (int j = 0; j < 8; ++j) {
        int d = c0v + j;
        ushort2 p; p.x = (unsigned short)v0[j]; p.y = (unsigned short)v1[j];
        *(ushort2*)&Vs[d][t0p ^ (d & 0x38)] = p;
      }
    }
    __syncthreads();

    // S^T = mfma(K, Q): D[m=t][n=s]; accSt[ti][si]
    f32x4 accSt[4][2] = {};
#pragma unroll
    for (int ks = 0; ks < 2; ++ks) {
      bf16x8 kf[4], qf[2];
#pragma unroll
      for (int ti = 0; ti < 4; ++ti) kf[ti] = frag64(Ks, ti * 16 + (lane & 15), ks * 32 + kc);
#pragma unroll
      for (int si = 0; si < 2; ++si) qf[si] = frag64(Qs, w * 32 + si * 16 + (lane & 15), ks * 32 + kc);
#pragma unroll
      for (int ti = 0; ti < 4; ++ti)
#pragma unroll
        for (int si = 0; si < 2; ++si)
          accSt[ti][si] = MFMA16(kf[ti], qf[si], accSt[ti][si]);
    }

    // decay + pack 4 bf16 (consecutive t at fixed s) -> one b64 LDS write
#pragma unroll
    for (int ti = 0; ti < 4; ++ti)
#pragma unroll
      for (int si = 0; si < 2; ++si) {
        int s = w * 32 + si * 16 + (lane & 15);
        int tb = ti * 16 + (lane >> 4) * 4;
        ushort4 pk;
#pragma unroll
        for (int r = 0; r < 4; ++r) {
          int diff = (s0 + s) - (t0 + tb + r);
          float dv = (diff >= 0) ? exp2f((float)diff * l2g) : 0.f;
          ((unsigned short*)&pk)[r] = f2bf(accSt[ti][si][r] * dv);
        }
        *(ushort4*)&Ss[s][tb] = pk;   // wave-private rows; in-order DS pipe
      }

    // Y += S V
#pragma unroll
    for (int ks = 0; ks < 2; ++ks) {
      bf16x8 af[2], vf[4];
#pragma unroll
      for (int mi = 0; mi < 2; ++mi) af[mi] = *(const bf16x8*)&Ss[w * 32 + mi * 16 + (lane & 15)][ks * 32 + kc];
#pragma unroll
      for (int ni = 0; ni < 4; ++ni) {
        int d = ni * 16 + (lane & 15);
        vf[ni] = *(const bf16x8*)&Vs[d][(ks * 32 + kc) ^ (d & 0x38)];
      }
#pragma unroll
      for (int mi = 0; mi < 2; ++mi)
#pragma unroll
        for (int ni = 0; ni < 4; ++ni)
          accY[mi][ni] = MFMA16(af[mi], vf[ni], accY[mi][ni]);
    }
  }

  // groupnorm + gate, write Ab
  float gw[4], gbv[4];
#pragma unroll
  for (int ni = 0; ni < 4; ++ni) {
    int d = ni * 16 + (lane & 15);
    gw[ni] = gnw[g * 64 + d];
    gbv[ni] = gnb[g * 64 + d];
  }
#pragma unroll
  for (int mi = 0; mi < 2; ++mi)
#pragma unroll
    for (int r = 0; r < 4; ++r) {
      float sm = 0.f, sq = 0.f;
#pragma unroll
      for (int ni = 0; ni < 4; ++ni) { float v = accY[mi][ni][r]; sm += v; sq += v * v; }
#pragma unroll
      for (int off = 1; off < 16; off <<= 1) { sm += __shfl_xor(sm, off); sq += __shfl_xor(sq, off); }
      float mean = sm * (1.f / 64.f);
      float var = sq * (1.f / 64.f) - mean * mean;
      float rstd = rsqrtf(var + 1e-5f);
      int row = w * 32 + mi * 16 + (lane >> 4) * 4 + r;
      size_t grow = (seqbase + s0 + row) * 512 + g * 64;
#pragma unroll
      for (int ni = 0; ni < 4; ++ni) {
        int d = ni * 16 + (lane & 15);
        float v = (accY[mi][ni][r] - mean) * rstd * gw[ni] + gbv[ni];
        float gate = bf2f(Gb[grow + d]);
        Ab[grow + d] = f2bf(v * gate);
      }
    }
}

// ---------------- K3: output GEMM ----------------
// tile 128x64, BK=64, 4 waves 2x2 (per-wave 64x32); grid (8 colblk, 64 rowblk)

__launch_bounds__(256)
__global__ void k_out(const unsigned short* __restrict__ Ab, const unsigned short* __restrict__ Wt,
                      float* __restrict__ out) {
  __shared__ __attribute__((aligned(16))) unsigned short As[128 * 64];
  __shared__ __attribute__((aligned(16))) unsigned short Bs[64 * 64];
  const int tid = threadIdx.x, lane = tid & 63, wid = tid >> 6;
  const int wr = wid >> 1, wc = wid & 1;
  const int cb = blockIdx.x, rb = blockIdx.y;

  f32x4 acc[4][2] = {};
  const int kc = (lane >> 4) * 8;
  const unsigned short* Ag = Ab + (size_t)(rb * 128) * 512;
  const unsigned short* Bg = Wt + (size_t)(cb * 64) * 512;

  for (int kt = 0; kt < 8; ++kt) {
    __syncthreads();
#pragma unroll
    for (int i = 0; i < 4; ++i) gload_chunk(Ag + kt * 64, 512, As, wid * 4 + i, lane);
#pragma unroll
    for (int i = 0; i < 2; ++i) gload_chunk(Bg + kt * 64, 512, Bs, wid * 2 + i, lane);
    __syncthreads();
#pragma unroll
    for (int ks = 0; ks < 2; ++ks) {
      bf16x8 a[4], b[2];
#pragma unroll
      for (int mi = 0; mi < 4; ++mi) a[mi] = frag64(As, wr * 64 + mi * 16 + (lane & 15), ks * 32 + kc);
#pragma unroll
      for (int ni = 0; ni < 2; ++ni) b[ni] = frag64(Bs, wc * 32 + ni * 16 + (lane & 15), ks * 32 + kc);
#pragma unroll
      for (int mi = 0; mi < 4; ++mi)
#pragma unroll
        for (int ni = 0; ni < 2; ++ni)
          acc[mi][ni] = MFMA16(a[mi], b[ni], acc[mi][ni]);
    }
  }

  const int row0 = rb * 128 + wr * 64;
  const int col0 = cb * 64 + wc * 32;
#pragma unroll
  for (int mi = 0; mi < 4; ++mi)
#pragma unroll
    for (int ni = 0; ni < 2; ++ni) {
      int col = col0 + ni * 16 + (lane & 15);
#pragma unroll
      for (int r = 0; r < 4; ++r) {
        int row = row0 + mi * 16 + (lane >> 4) * 4 + r;
        out[(size_t)row * 512 + col] = acc[mi][ni][r];
      }
    }
}

// ---------------- launch ----------------

extern "C" void kernel_launch(void* const* d_in, const int* in_sizes, int n_in,
                              void* d_out, int out_size, void* d_ws, size_t ws_size,
                              hipStream_t stream) {
  const float* X   = (const float*)d_in[0];
  const float* WQ  = (const float*)d_in[1];
  const float* WK  = (const float*)d_in[2];
  const float* WV  = (const float*)d_in[3];
  const float* WG  = (const float*)d_in[4];
  const float* WO  = (const float*)d_in[5];
  const float* gnw = (const float*)d_in[6];
  const float* gnb = (const float*)d_in[7];
  float* out = (float*)d_out;

  char* ws = (char*)d_ws;
  const size_t SZ_BUF = (size_t)8192 * 512 * 2;   // 8 MB bf16
  unsigned short* Xb   = (unsigned short*)(ws);
  unsigned short* Qb   = (unsigned short*)(ws + SZ_BUF);
  unsigned short* Kb   = (unsigned short*)(ws + 2 * SZ_BUF);
  unsigned short* Vb   = (unsigned short*)(ws + 3 * SZ_BUF);
  unsigned short* Gb   = (unsigned short*)(ws + 4 * SZ_BUF);
  unsigned short* Ab   = (unsigned short*)(ws + 5 * SZ_BUF);
  unsigned short* Wcat = (unsigned short*)(ws + 6 * SZ_BUF);            // 2 MB
  unsigned short* WoT  = (unsigned short*)(ws + 6 * SZ_BUF + 2097152);  // 0.5 MB
  float* sinT = (float*)(ws + 6 * SZ_BUF + 2097152 + 524288);
  float* cosT = sinT + 65536;
  float* scT  = cosT + 65536;
  float* iscT = scT + 65536;

  k_tables<<<256, 256, 0, stream>>>(sinT, cosT, scT, iscT);
  k_x2bf<<<4096, 256, 0, stream>>>(X, Xb);
  k_wcat<<<4096, 256, 0, stream>>>(WQ, WK, WV, WG, Wcat);
  k_wo<<<1024, 256, 0, stream>>>(WO, WoT);
  k_proj<<<dim3(16, 64), 256, 0, stream>>>(Xb, Wcat, sinT, cosT, scT, iscT, Qb, Kb, Vb, Gb);
  k_ret<<<dim3(8, 8, 8), 256, 0, stream>>>(Qb, Kb, Vb, Gb, gnw, gnb, Ab);
  k_out<<<dim3(8, 64), 256, 0, stream>>>(Ab, WoT, out);
}

// Round 3
// 166.133 us; speedup vs baseline: 1.3427x; 1.2557x over previous
//
#include <hip/hip_runtime.h>
#include <hip/hip_bf16.h>
#include <math.h>

// MultiScaleRetention: B=2,N=4,S=1024,H=512, HEADS=8, HEAD=64
//  k_prep: X->bf16, WcatT, WoT, packed xpos tables (one launch)
//  k_proj: proj GEMM + xpos/silu epilogue -> Qb,Kb,Vb,Gb  (double-buffered, vmcnt(8))
//  k_ret : retention + factorized decay + groupnorm + gate -> Ab (1-tile-ahead prefetch)
//  k_out : out GEMM -> fp32                               (double-buffered, vmcnt(6))
// All main loops use raw s_barrier + counted vmcnt (T3/T4); __syncthreads would
// drain vmcnt(0) and kill the pipeline.

typedef __attribute__((ext_vector_type(8))) short bf16x8;
typedef __attribute__((ext_vector_type(4))) float f32x4;

#define MFMA16(a, b, c) __builtin_amdgcn_mfma_f32_16x16x32_bf16(a, b, c, 0, 0, 0)
#define BAR() __builtin_amdgcn_s_barrier()
#define WAITV(n) asm volatile("s_waitcnt vmcnt(" #n ")" ::: "memory")
#define LGKM0() asm volatile("s_waitcnt lgkmcnt(0)" ::: "memory")

__device__ __forceinline__ unsigned short f2bf(float f) {
  union { float f; unsigned u; } x; x.f = f;
  unsigned r = x.u + 0x7FFFu + ((x.u >> 16) & 1u);
  return (unsigned short)(r >> 16);
}
__device__ __forceinline__ float bf2f(unsigned short b) {
  union { unsigned u; float f; } x; x.u = ((unsigned)b) << 16;
  return x.f;
}

// 1KB chunk = 8 rows x 128B of a [R][64]-bf16 LDS tile. LDS dest linear
// (gload_lds requirement); global source column pre-swizzled so reads use
// byte ^ ((row&7)<<4) conflict-free.
__device__ __forceinline__ void gload_chunk(const unsigned short* gtile, size_t gstride,
                                            unsigned short* lds, int chunk, int lane) {
  int r = (chunk << 3) + (lane >> 3);
  int colel = ((lane & 7) ^ (lane >> 3)) << 3;
  const unsigned short* gp = gtile + (size_t)r * gstride + colel;
  __builtin_amdgcn_global_load_lds(
      (const __attribute__((address_space(1))) unsigned int*)gp,
      (__attribute__((address_space(3))) unsigned int*)((char*)lds + (chunk << 10)),
      16, 0, 0);
}

__device__ __forceinline__ bf16x8 frag64(const unsigned short* lds, int row, int colel) {
  return *(const bf16x8*)((const char*)lds + row * 128 + ((colel * 2) ^ ((row & 7) << 4)));
}

// ---------------- merged prep ----------------
// blocks [0,4096): X->bf16 ; [4096,8192): Wcat ; [8192,9216): WoT ; [9216,9344): tables

__global__ void k_prep(const float* __restrict__ X, const float* __restrict__ WQ,
                       const float* __restrict__ WK, const float* __restrict__ WV,
                       const float* __restrict__ WG, const float* __restrict__ WO,
                       unsigned short* __restrict__ Xb, unsigned short* __restrict__ Wcat,
                       unsigned short* __restrict__ WoT,
                       float2* __restrict__ qtab, float2* __restrict__ ktab) {
  int b = blockIdx.x, tid = threadIdx.x;
  if (b < 4096) {
    int idx = b * 256 + tid;
    float4 v = ((const float4*)X)[idx];
    ushort4 o;
    o.x = f2bf(v.x); o.y = f2bf(v.y); o.z = f2bf(v.z); o.w = f2bf(v.w);
    ((ushort4*)Xb)[idx] = o;
  } else if (b < 8192) {
    int idx = (b - 4096) * 256 + tid;          // n*512 + k, n in [0,2048)
    int n = idx >> 9, k = idx & 511;
    float w;
    if (n < 1536) {
      const float* W = (n < 512) ? WQ : (n < 1024 ? WK : WV);
      int c = n & 511; int g = c >> 6, d = c & 63;
      w = W[((size_t)g * 512 + k) * 64 + d];
    } else {
      w = WG[(size_t)k * 512 + (n - 1536)];
    }
    Wcat[idx] = f2bf(w);
  } else if (b < 9216) {
    int idx = (b - 8192) * 256 + tid;          // n*512 + k
    int n = idx >> 9, k = idx & 511;
    WoT[idx] = f2bf(WO[(size_t)k * 512 + n]);
  } else {
    int idx = (b - 9216) * 256 + tid;          // s*32 + i
    int s = idx >> 5, i = idx & 31;
    double invf = pow(10000.0, -(double)i / 32.0);
    double ang = (double)s * invf;
    double sn = sin(ang), cs = cos(ang);
    double sv = (2.0 * i + 0.4 * 64.0) / (1.4 * 64.0);
    double sc = pow(sv, (double)s / 512.0);
    qtab[idx] = make_float2((float)(cs * sc), (float)(sn * sc));
    ktab[idx] = make_float2((float)(cs / sc), (float)(sn / sc));
  }
}

// ---------------- K1: projection GEMM + xpos/silu epilogue ----------------
// tile 128x128, BK=64 double-buffered, 4 waves 2x2; grid (16 colblk, 64 rowblk)

__launch_bounds__(256)
__global__ void k_proj(const unsigned short* __restrict__ Xb, const unsigned short* __restrict__ Wt,
                       const float2* __restrict__ qtab, const float2* __restrict__ ktab,
                       unsigned short* __restrict__ Qb, unsigned short* __restrict__ Kb,
                       unsigned short* __restrict__ Vb, unsigned short* __restrict__ Gb) {
  __shared__ __attribute__((aligned(16))) unsigned short As[2][128 * 64];
  __shared__ __attribute__((aligned(16))) unsigned short Bs[2][128 * 64];
  const int tid = threadIdx.x, lane = tid & 63, wid = tid >> 6;
  const int wr = wid >> 1, wc = wid & 1;
  const int cb = blockIdx.x, rb = blockIdx.y;

  f32x4 acc[4][4] = {};
  const int kc = (lane >> 4) * 8;
  const unsigned short* Ag = Xb + (size_t)(rb * 128) * 512;
  const unsigned short* Bg = Wt + (size_t)(cb * 128) * 512;

#define PSTAGE(kt, buf)                                          \
  {                                                              \
    _Pragma("unroll") for (int i = 0; i < 4; ++i) {              \
      gload_chunk(Ag + (kt) * 64, 512, As[buf], wid * 4 + i, lane); \
      gload_chunk(Bg + (kt) * 64, 512, Bs[buf], wid * 4 + i, lane); \
    }                                                            \
  }

  PSTAGE(0, 0);
  for (int kt = 0; kt < 8; ++kt) {
    const int cur = kt & 1;
    if (kt < 7) {
      PSTAGE(kt + 1, cur ^ 1);
      WAITV(8);                 // current tile's 8 loads done; next 8 in flight
    } else {
      WAITV(0);
    }
    BAR();
#pragma unroll
    for (int ks = 0; ks < 2; ++ks) {
      bf16x8 a[4], b[4];
#pragma unroll
      for (int mi = 0; mi < 4; ++mi) a[mi] = frag64(As[cur], wr * 64 + mi * 16 + (lane & 15), ks * 32 + kc);
#pragma unroll
      for (int ni = 0; ni < 4; ++ni) b[ni] = frag64(Bs[cur], wc * 64 + ni * 16 + (lane & 15), ks * 32 + kc);
#pragma unroll
      for (int mi = 0; mi < 4; ++mi)
#pragma unroll
        for (int ni = 0; ni < 4; ++ni)
          acc[mi][ni] = MFMA16(a[mi], b[ni], acc[mi][ni]);
    }
    LGKM0();                    // all ds_reads of this tile complete
    BAR();                      // safe for next iter to overwrite other buffer
  }
#undef PSTAGE

  const int row0 = rb * 128 + wr * 64;
  const int colbase = cb * 128 + wc * 64;
  const int cls = cb >> 2;                  // 0=Q 1=K 2=V 3=gate (block-uniform)
  const float sgn = (lane & 1) ? 1.f : -1.f;

  if (cls <= 1) {
    const float2* tab = (cls == 0) ? qtab : ktab;
    unsigned short* dst = (cls == 0) ? Qb : Kb;
#pragma unroll
    for (int mi = 0; mi < 4; ++mi)
#pragma unroll
      for (int ni = 0; ni < 4; ++ni) {
        int d = ni * 16 + (lane & 15);
        int i = d >> 1;
        int c = (colbase + d) & 511;
#pragma unroll
        for (int r = 0; r < 4; ++r) {
          int row = row0 + mi * 16 + (lane >> 4) * 4 + r;
          int s = row & 1023;
          float v = acc[mi][ni][r];
          float p = __shfl_xor(v, 1);
          float2 t = tab[s * 32 + i];
          dst[(size_t)row * 512 + c] = f2bf(v * t.x + sgn * p * t.y);
        }
      }
  } else {
    unsigned short* dst = (cls == 2) ? Vb : Gb;
#pragma unroll
    for (int mi = 0; mi < 4; ++mi)
#pragma unroll
      for (int ni = 0; ni < 4; ++ni) {
        int c = (colbase + ni * 16 + (lane & 15)) & 511;
#pragma unroll
        for (int r = 0; r < 4; ++r) {
          int row = row0 + mi * 16 + (lane >> 4) * 4 + r;
          float v = acc[mi][ni][r];
          if (cls == 3) v = v / (1.f + __expf(-v));   // silu
          dst[(size_t)row * 512 + c] = f2bf(v);
        }
      }
  }
}

// ---------------- K2: retention + decay + groupnorm + gate ----------------
// grid (8 sblk, 8 head, 8 seq), 4 waves; 128 q-rows, 64 kv-rows/tile, 1-ahead prefetch

__launch_bounds__(256)
__global__ void k_ret(const unsigned short* __restrict__ Qb, const unsigned short* __restrict__ Kb,
                      const unsigned short* __restrict__ Vb, const unsigned short* __restrict__ Gb,
                      const float* __restrict__ gnw, const float* __restrict__ gnb,
                      unsigned short* __restrict__ Ab) {
  __shared__ __attribute__((aligned(16))) unsigned short Qs[128 * 64];
  __shared__ __attribute__((aligned(16))) unsigned short Ks[2][64 * 64];
  __shared__ __attribute__((aligned(16))) unsigned short Vs[2][64][72];
  __shared__ __attribute__((aligned(16))) unsigned short Ss[128][72];
  const int sblk = blockIdx.x, g = blockIdx.y, bn = blockIdx.z;
  const int tid = threadIdx.x, lane = tid & 63, w = tid >> 6;

  const float lg0 = logf(1.f / 32.f), lg1 = logf(1.f / 512.f);
  const float gam = 1.f - expf(lg0 + g * (lg1 - lg0) / 7.f);
  const float l2g = log2f(gam);

  const int s0 = sblk * 128;
  const size_t seqbase = (size_t)bn * 1024;
  const int kc = (lane >> 4) * 8;
  const int ntt = 2 * sblk + 2;

  // per-thread t-column decay factors gamma^(-(tb+r)) (tile-invariant)
  float cf[16];
#pragma unroll
  for (int ti = 0; ti < 4; ++ti)
#pragma unroll
    for (int r = 0; r < 4; ++r)
      cf[ti * 4 + r] = exp2f(l2g * (float)(-(ti * 16 + (lane >> 4) * 4 + r)));
  const int sRow[2] = { w * 32 + (lane & 15), w * 32 + 16 + (lane & 15) };

  // V staging mapping: thread -> 2 rows x 8 cols
  const int t0p = (tid >> 3) * 2;
  const int c0v = (tid & 7) * 8;
  const unsigned short* Vg = Vb + seqbase * 512 + g * 64 + c0v;

#define KSTAGE(t, buf)                                                        \
  {                                                                           \
    gload_chunk(Kb + (seqbase + (t) * 64) * 512 + g * 64, 512, Ks[buf], w * 2 + 0, lane); \
    gload_chunk(Kb + (seqbase + (t) * 64) * 512 + g * 64, 512, Ks[buf], w * 2 + 1, lane); \
  }
#define VLOAD(t, r0, r1)                                                      \
  {                                                                           \
    r0 = *(const bf16x8*)(Vg + (size_t)((t) * 64 + t0p) * 512);               \
    r1 = *(const bf16x8*)(Vg + (size_t)((t) * 64 + t0p + 1) * 512);           \
  }
#define VWRITE(buf, r0, r1)                                                   \
  {                                                                           \
    _Pragma("unroll") for (int j = 0; j < 8; ++j) {                           \
      int d = c0v + j;                                                        \
      ushort2 pp; pp.x = (unsigned short)r0[j]; pp.y = (unsigned short)r1[j]; \
      *(ushort2*)&Vs[buf][d][t0p ^ (d & 0x38)] = pp;                          \
    }                                                                         \
  }

  bf16x8 vA0, vA1, vB0, vB1;

  // prologue: Q(4) + K0(2) + V0(2) = 8 vmem
  const unsigned short* Qg = Qb + (seqbase + s0) * 512 + g * 64;
#pragma unroll
  for (int i = 0; i < 4; ++i) gload_chunk(Qg, 512, Qs, w * 4 + i, lane);
  KSTAGE(0, 0);
  VLOAD(0, vA0, vA1);
  WAITV(0);
  VWRITE(0, vA0, vA1);
  KSTAGE(1, 1);                 // ntt >= 2 always
  VLOAD(1, vB0, vB1);
  LGKM0();
  BAR();

  // hoist Q fragments (rows w*32..w*32+31 were self-staged; Ks/Vs need the BAR)
  bf16x8 qreg[2][2];
#pragma unroll
  for (int ks = 0; ks < 2; ++ks)
#pragma unroll
    for (int si = 0; si < 2; ++si)
      qreg[ks][si] = frag64(Qs, w * 32 + si * 16 + (lane & 15), ks * 32 + kc);

  f32x4 accY[2][4] = {};

  auto body = [&](int tt, int cur, bf16x8& w0, bf16x8& w1, bf16x8& l0, bf16x8& l1) {
    const int t0 = tt * 64;
    // S^T = mfma(K, Q): D[m=t][n=s]
    f32x4 accSt[4][2] = {};
#pragma unroll
    for (int ks = 0; ks < 2; ++ks) {
      bf16x8 kf[4];
#pragma unroll
      for (int ti = 0; ti < 4; ++ti) kf[ti] = frag64(Ks[cur], ti * 16 + (lane & 15), ks * 32 + kc);
#pragma unroll
      for (int ti = 0; ti < 4; ++ti)
#pragma unroll
        for (int si = 0; si < 2; ++si)
          accSt[ti][si] = MFMA16(kf[ti], qreg[ks][si], accSt[ti][si]);
    }

    // factorized decay: dv = gamma^(s0+s-t0) * gamma^(-(tb+r))
    float rf[2];
    rf[0] = exp2f(l2g * (float)(s0 + sRow[0] - t0));
    rf[1] = exp2f(l2g * (float)(s0 + sRow[1] - t0));
    if (tt >= 2 * sblk) {       // diagonal tiles: need causal mask
#pragma unroll
      for (int ti = 0; ti < 4; ++ti)
#pragma unroll
        for (int si = 0; si < 2; ++si) {
          int tb = ti * 16 + (lane >> 4) * 4;
          ushort4 pk;
#pragma unroll
          for (int r = 0; r < 4; ++r) {
            int diff = (s0 + sRow[si]) - (t0 + tb + r);
            float dv = (diff >= 0) ? rf[si] * cf[ti * 4 + r] : 0.f;
            ((unsigned short*)&pk)[r] = f2bf(accSt[ti][si][r] * dv);
          }
          *(ushort4*)&Ss[sRow[si]][tb] = pk;
        }
    } else {
#pragma unroll
      for (int ti = 0; ti < 4; ++ti)
#pragma unroll
        for (int si = 0; si < 2; ++si) {
          int tb = ti * 16 + (lane >> 4) * 4;
          ushort4 pk;
#pragma unroll
          for (int r = 0; r < 4; ++r)
            ((unsigned short*)&pk)[r] = f2bf(accSt[ti][si][r] * rf[si] * cf[ti * 4 + r]);
          *(ushort4*)&Ss[sRow[si]][tb] = pk;
        }
    }

    // Y += S V   (Ss rows are wave-private: in-order DS pipe, no barrier)
#pragma unroll
    for (int ks = 0; ks < 2; ++ks) {
      bf16x8 af[2], vf[4];
#pragma unroll
      for (int mi = 0; mi < 2; ++mi) af[mi] = *(const bf16x8*)&Ss[sRow[mi]][ks * 32 + kc];
#pragma unroll
      for (int ni = 0; ni < 4; ++ni) {
        int d = ni * 16 + (lane & 15);
        vf[ni] = *(const bf16x8*)&Vs[cur][d][(ks * 32 + kc) ^ (d & 0x38)];
      }
#pragma unroll
      for (int mi = 0; mi < 2; ++mi)
#pragma unroll
        for (int ni = 0; ni < 4; ++ni)
          accY[mi][ni] = MFMA16(af[mi], vf[ni], accY[mi][ni]);
    }

    LGKM0();
    BAR();                       // everyone done reading Ks[cur], Vs[cur]
    if (tt + 1 < ntt) {
      WAITV(0);                  // K(t+1) in LDS, V(t+1) in regs (flew during compute)
      VWRITE(cur ^ 1, w0, w1);
      if (tt + 2 < ntt) {        // prefetch t+2 into the buffer just freed
        KSTAGE(tt + 2, cur);
        VLOAD(tt + 2, l0, l1);
      }
      LGKM0();
      BAR();
    }
  };

  for (int tt = 0; tt < ntt; tt += 2) {
    body(tt, 0, vB0, vB1, vA0, vA1);
    body(tt + 1, 1, vA0, vA1, vB0, vB1);
  }

  // groupnorm + gate, write Ab
  float gw[4], gbv[4];
#pragma unroll
  for (int ni = 0; ni < 4; ++ni) {
    int d = ni * 16 + (lane & 15);
    gw[ni] = gnw[g * 64 + d];
    gbv[ni] = gnb[g * 64 + d];
  }
#pragma unroll
  for (int mi = 0; mi < 2; ++mi)
#pragma unroll
    for (int r = 0; r < 4; ++r) {
      float sm = 0.f, sq = 0.f;
#pragma unroll
      for (int ni = 0; ni < 4; ++ni) { float v = accY[mi][ni][r]; sm += v; sq += v * v; }
#pragma unroll
      for (int off = 1; off < 16; off <<= 1) { sm += __shfl_xor(sm, off); sq += __shfl_xor(sq, off); }
      float mean = sm * (1.f / 64.f);
      float var = sq * (1.f / 64.f) - mean * mean;
      float rstd = rsqrtf(var + 1e-5f);
      int row = w * 32 + mi * 16 + (lane >> 4) * 4 + r;
      size_t grow = (seqbase + s0 + row) * 512 + g * 64;
#pragma unroll
      for (int ni = 0; ni < 4; ++ni) {
        int d = ni * 16 + (lane & 15);
        float v = (accY[mi][ni][r] - mean) * rstd * gw[ni] + gbv[ni];
        float gate = bf2f(Gb[grow + d]);
        Ab[grow + d] = f2bf(v * gate);
      }
    }
#undef KSTAGE
#undef VLOAD
#undef VWRITE
}

// ---------------- K3: output GEMM ----------------
// tile 128x64, BK=64 double-buffered, 4 waves 2x2; grid (8 colblk, 64 rowblk)

__launch_bounds__(256)
__global__ void k_out(const unsigned short* __restrict__ Ab, const unsigned short* __restrict__ Wt,
                      float* __restrict__ out) {
  __shared__ __attribute__((aligned(16))) unsigned short As[2][128 * 64];
  __shared__ __attribute__((aligned(16))) unsigned short Bs[2][64 * 64];
  const int tid = threadIdx.x, lane = tid & 63, wid = tid >> 6;
  const int wr = wid >> 1, wc = wid & 1;
  const int cb = blockIdx.x, rb = blockIdx.y;

  f32x4 acc[4][2] = {};
  const int kc = (lane >> 4) * 8;
  const unsigned short* Ag = Ab + (size_t)(rb * 128) * 512;
  const unsigned short* Bg = Wt + (size_t)(cb * 64) * 512;

#define OSTAGE(kt, buf)                                                  \
  {                                                                      \
    _Pragma("unroll") for (int i = 0; i < 4; ++i)                        \
        gload_chunk(Ag + (kt) * 64, 512, As[buf], wid * 4 + i, lane);    \
    _Pragma("unroll") for (int i = 0; i < 2; ++i)                        \
        gload_chunk(Bg + (kt) * 64, 512, Bs[buf], wid * 2 + i, lane);    \
  }

  OSTAGE(0, 0);
  for (int kt = 0; kt < 8; ++kt) {
    const int cur = kt & 1;
    if (kt < 7) {
      OSTAGE(kt + 1, cur ^ 1);
      WAITV(6);
    } else {
      WAITV(0);
    }
    BAR();
#pragma unroll
    for (int ks = 0; ks < 2; ++ks) {
      bf16x8 a[4], b[2];
#pragma unroll
      for (int mi = 0; mi < 4; ++mi) a[mi] = frag64(As[cur], wr * 64 + mi * 16 + (lane & 15), ks * 32 + kc);
#pragma unroll
      for (int ni = 0; ni < 2; ++ni) b[ni] = frag64(Bs[cur], wc * 32 + ni * 16 + (lane & 15), ks * 32 + kc);
#pragma unroll
      for (int mi = 0; mi < 4; ++mi)
#pragma unroll
        for (int ni = 0; ni < 2; ++ni)
          acc[mi][ni] = MFMA16(a[mi], b[ni], acc[mi][ni]);
    }
    LGKM0();
    BAR();
  }
#undef OSTAGE

  const int row0 = rb * 128 + wr * 64;
  const int col0 = cb * 64 + wc * 32;
#pragma unroll
  for (int mi = 0; mi < 4; ++mi)
#pragma unroll
    for (int ni = 0; ni < 2; ++ni) {
      int col = col0 + ni * 16 + (lane & 15);
#pragma unroll
      for (int r = 0; r < 4; ++r) {
        int row = row0 + mi * 16 + (lane >> 4) * 4 + r;
        out[(size_t)row * 512 + col] = acc[mi][ni][r];
      }
    }
}

// ---------------- launch ----------------

extern "C" void kernel_launch(void* const* d_in, const int* in_sizes, int n_in,
                              void* d_out, int out_size, void* d_ws, size_t ws_size,
                              hipStream_t stream) {
  const float* X   = (const float*)d_in[0];
  const float* WQ  = (const float*)d_in[1];
  const float* WK  = (const float*)d_in[2];
  const float* WV  = (const float*)d_in[3];
  const float* WG  = (const float*)d_in[4];
  const float* WO  = (const float*)d_in[5];
  const float* gnw = (const float*)d_in[6];
  const float* gnb = (const float*)d_in[7];
  float* out = (float*)d_out;

  char* ws = (char*)d_ws;
  const size_t SZ_BUF = (size_t)8192 * 512 * 2;   // 8 MB bf16
  unsigned short* Xb   = (unsigned short*)(ws);
  unsigned short* Qb   = (unsigned short*)(ws + SZ_BUF);
  unsigned short* Kb   = (unsigned short*)(ws + 2 * SZ_BUF);
  unsigned short* Vb   = (unsigned short*)(ws + 3 * SZ_BUF);
  unsigned short* Gb   = (unsigned short*)(ws + 4 * SZ_BUF);
  unsigned short* Ab   = (unsigned short*)(ws + 5 * SZ_BUF);
  unsigned short* Wcat = (unsigned short*)(ws + 6 * SZ_BUF);            // 2 MB
  unsigned short* WoT  = (unsigned short*)(ws + 6 * SZ_BUF + 2097152);  // 0.5 MB
  float2* qtab = (float2*)(ws + 6 * SZ_BUF + 2097152 + 524288);         // 256 KB
  float2* ktab = qtab + 32768;                                          // 256 KB

  k_prep<<<9344, 256, 0, stream>>>(X, WQ, WK, WV, WG, WO, Xb, Wcat, WoT, qtab, ktab);
  k_proj<<<dim3(16, 64), 256, 0, stream>>>(Xb, Wcat, qtab, ktab, Qb, Kb, Vb, Gb);
  k_ret<<<dim3(8, 8, 8), 256, 0, stream>>>(Qb, Kb, Vb, Gb, gnw, gnb, Ab);
  k_out<<<dim3(8, 64), 256, 0, stream>>>(Ab, WoT, out);
}

// Round 4
// 158.088 us; speedup vs baseline: 1.4110x; 1.0509x over previous
//
#include <hip/hip_runtime.h>
#include <hip/hip_bf16.h>
#include <math.h>

// MultiScaleRetention: B=2,N=4,S=1024,H=512, HEADS=8, HEAD=64
//  k_prep: X->bf16, WcatT, WoT, packed xpos tables (one launch)
//  k_proj: proj GEMM 256x256 tile, 8 waves (2x4), per-wave 128x64, dbuf BK=64,
//          counted vmcnt; xpos/silu epilogue -> Qb,Kb,Vb,Gb
//  k_ret : retention + factorized decay + groupnorm + gate -> Ab
//          (1-ahead prefetch, CU-pair load balancing: sblk f paired with 7-f)
//  k_out : out GEMM 128x64 tile -> fp32
// Raw s_barrier + counted vmcnt everywhere (T3/T4); __syncthreads would drain
// vmcnt(0) and kill the pipeline.

typedef __attribute__((ext_vector_type(8))) short bf16x8;
typedef __attribute__((ext_vector_type(4))) float f32x4;

#define MFMA16(a, b, c) __builtin_amdgcn_mfma_f32_16x16x32_bf16(a, b, c, 0, 0, 0)
#define BAR() __builtin_amdgcn_s_barrier()
#define WAITV(n) asm volatile("s_waitcnt vmcnt(" #n ")" ::: "memory")
#define LGKM0() asm volatile("s_waitcnt lgkmcnt(0)" ::: "memory")

__device__ __forceinline__ unsigned short f2bf(float f) {
  union { float f; unsigned u; } x; x.f = f;
  unsigned r = x.u + 0x7FFFu + ((x.u >> 16) & 1u);
  return (unsigned short)(r >> 16);
}
__device__ __forceinline__ float bf2f(unsigned short b) {
  union { unsigned u; float f; } x; x.u = ((unsigned)b) << 16;
  return x.f;
}

// 1KB chunk = 8 rows x 128B of a [R][64]-bf16 LDS tile. LDS dest linear
// (gload_lds requirement); global source column pre-swizzled so reads use
// byte ^ ((row&7)<<4) conflict-free.
__device__ __forceinline__ void gload_chunk(const unsigned short* gtile, size_t gstride,
                                            unsigned short* lds, int chunk, int lane) {
  int r = (chunk << 3) + (lane >> 3);
  int colel = ((lane & 7) ^ (lane >> 3)) << 3;
  const unsigned short* gp = gtile + (size_t)r * gstride + colel;
  __builtin_amdgcn_global_load_lds(
      (const __attribute__((address_space(1))) unsigned int*)gp,
      (__attribute__((address_space(3))) unsigned int*)((char*)lds + (chunk << 10)),
      16, 0, 0);
}

__device__ __forceinline__ bf16x8 frag64(const unsigned short* lds, int row, int colel) {
  return *(const bf16x8*)((const char*)lds + row * 128 + ((colel * 2) ^ ((row & 7) << 4)));
}

// ---------------- merged prep ----------------
// blocks [0,4096): X->bf16 ; [4096,8192): Wcat ; [8192,9216): WoT ; [9216,9344): tables

__global__ void k_prep(const float* __restrict__ X, const float* __restrict__ WQ,
                       const float* __restrict__ WK, const float* __restrict__ WV,
                       const float* __restrict__ WG, const float* __restrict__ WO,
                       unsigned short* __restrict__ Xb, unsigned short* __restrict__ Wcat,
                       unsigned short* __restrict__ WoT,
                       float2* __restrict__ qtab, float2* __restrict__ ktab) {
  int b = blockIdx.x, tid = threadIdx.x;
  if (b < 4096) {
    int idx = b * 256 + tid;
    float4 v = ((const float4*)X)[idx];
    ushort4 o;
    o.x = f2bf(v.x); o.y = f2bf(v.y); o.z = f2bf(v.z); o.w = f2bf(v.w);
    ((ushort4*)Xb)[idx] = o;
  } else if (b < 8192) {
    int idx = (b - 4096) * 256 + tid;          // n*512 + k, n in [0,2048)
    int n = idx >> 9, k = idx & 511;
    float w;
    if (n < 1536) {
      const float* W = (n < 512) ? WQ : (n < 1024 ? WK : WV);
      int c = n & 511; int g = c >> 6, d = c & 63;
      w = W[((size_t)g * 512 + k) * 64 + d];
    } else {
      w = WG[(size_t)k * 512 + (n - 1536)];
    }
    Wcat[idx] = f2bf(w);
  } else if (b < 9216) {
    int idx = (b - 8192) * 256 + tid;          // n*512 + k
    int n = idx >> 9, k = idx & 511;
    WoT[idx] = f2bf(WO[(size_t)k * 512 + n]);
  } else {
    int idx = (b - 9216) * 256 + tid;          // s*32 + i
    int s = idx >> 5, i = idx & 31;
    double invf = pow(10000.0, -(double)i / 32.0);
    double ang = (double)s * invf;
    double sn = sin(ang), cs = cos(ang);
    double sv = (2.0 * i + 0.4 * 64.0) / (1.4 * 64.0);
    double sc = pow(sv, (double)s / 512.0);
    qtab[idx] = make_float2((float)(cs * sc), (float)(sn * sc));
    ktab[idx] = make_float2((float)(cs / sc), (float)(sn / sc));
  }
}

// ---------------- K1: projection GEMM + xpos/silu epilogue ----------------
// tile 256x256, BK=64 double-buffered, 8 waves 2x4 (per-wave 128x64);
// grid (8 colblk, 32 rowblk) = 256 blocks = 1/CU, LDS 128KB

__launch_bounds__(512, 2)
__global__ void k_proj(const unsigned short* __restrict__ Xb, const unsigned short* __restrict__ Wt,
                       const float2* __restrict__ qtab, const float2* __restrict__ ktab,
                       unsigned short* __restrict__ Qb, unsigned short* __restrict__ Kb,
                       unsigned short* __restrict__ Vb, unsigned short* __restrict__ Gb) {
  __shared__ __attribute__((aligned(16))) unsigned short As[2][256 * 64];
  __shared__ __attribute__((aligned(16))) unsigned short Bs[2][256 * 64];
  const int tid = threadIdx.x, lane = tid & 63, wid = tid >> 6;
  const int wr = wid >> 2, wc = wid & 3;     // 2 x 4 waves
  const int cb = blockIdx.x, rb = blockIdx.y;

  f32x4 acc[8][4] = {};
  const int kc = (lane >> 4) * 8;
  const unsigned short* Ag = Xb + (size_t)(rb * 256) * 512;
  const unsigned short* Bg = Wt + (size_t)(cb * 256) * 512;

#define PSTAGE(kt, buf)                                             \
  {                                                                 \
    _Pragma("unroll") for (int i = 0; i < 4; ++i) {                 \
      gload_chunk(Ag + (kt) * 64, 512, As[buf], wid * 4 + i, lane); \
      gload_chunk(Bg + (kt) * 64, 512, Bs[buf], wid * 4 + i, lane); \
    }                                                               \
  }

  PSTAGE(0, 0);
  for (int kt = 0; kt < 8; ++kt) {
    const int cur = kt & 1;
    if (kt < 7) {
      PSTAGE(kt + 1, cur ^ 1);
      WAITV(8);                 // own 8 loads of tile kt done; 8 of kt+1 in flight
    } else {
      WAITV(0);
    }
    BAR();
#pragma unroll
    for (int ks = 0; ks < 2; ++ks) {
      bf16x8 a[8], b[4];
#pragma unroll
      for (int mi = 0; mi < 8; ++mi) a[mi] = frag64(As[cur], wr * 128 + mi * 16 + (lane & 15), ks * 32 + kc);
#pragma unroll
      for (int ni = 0; ni < 4; ++ni) b[ni] = frag64(Bs[cur], wc * 64 + ni * 16 + (lane & 15), ks * 32 + kc);
#pragma unroll
      for (int mi = 0; mi < 8; ++mi)
#pragma unroll
        for (int ni = 0; ni < 4; ++ni)
          acc[mi][ni] = MFMA16(a[mi], b[ni], acc[mi][ni]);
    }
    LGKM0();                    // all ds_reads of this tile complete
    BAR();                      // safe for next iter to overwrite other buffer
  }
#undef PSTAGE

  const int row0 = rb * 256 + wr * 128;
  const int colbase = cb * 256 + wc * 64;
  const int cls = cb >> 1;                  // 0=Q 1=K 2=V 3=gate (block-uniform)
  const float sgn = (lane & 1) ? 1.f : -1.f;

  if (cls <= 1) {
    const float2* tab = (cls == 0) ? qtab : ktab;
    unsigned short* dst = (cls == 0) ? Qb : Kb;
#pragma unroll
    for (int mi = 0; mi < 8; ++mi)
#pragma unroll
      for (int ni = 0; ni < 4; ++ni) {
        int d = ((colbase + ni * 16 + (lane & 15)) & 63);
        int i = d >> 1;
        int c = (colbase + ni * 16 + (lane & 15)) & 511;
#pragma unroll
        for (int r = 0; r < 4; ++r) {
          int row = row0 + mi * 16 + (lane >> 4) * 4 + r;
          int s = row & 1023;
          float v = acc[mi][ni][r];
          float p = __shfl_xor(v, 1);
          float2 t = tab[s * 32 + i];
          dst[(size_t)row * 512 + c] = f2bf(v * t.x + sgn * p * t.y);
        }
      }
  } else {
    unsigned short* dst = (cls == 2) ? Vb : Gb;
#pragma unroll
    for (int mi = 0; mi < 8; ++mi)
#pragma unroll
      for (int ni = 0; ni < 4; ++ni) {
        int c = (colbase + ni * 16 + (lane & 15)) & 511;
#pragma unroll
        for (int r = 0; r < 4; ++r) {
          int row = row0 + mi * 16 + (lane >> 4) * 4 + r;
          float v = acc[mi][ni][r];
          if (cls == 3) v = v / (1.f + __expf(-v));   // silu
          dst[(size_t)row * 512 + c] = f2bf(v);
        }
      }
  }
}

// ---------------- K2: retention + decay + groupnorm + gate ----------------
// flat grid 512; CU-pair balancing: blocks u and u+256 get sblk f and 7-f
// (co-resident pairs differ by 256 -> per-CU tile work constant at 18)

__launch_bounds__(256)
__global__ void k_ret(const unsigned short* __restrict__ Qb, const unsigned short* __restrict__ Kb,
                      const unsigned short* __restrict__ Vb, const unsigned short* __restrict__ Gb,
                      const float* __restrict__ gnw, const float* __restrict__ gnb,
                      unsigned short* __restrict__ Ab) {
  __shared__ __attribute__((aligned(16))) unsigned short Qs[128 * 64];
  __shared__ __attribute__((aligned(16))) unsigned short Ks[2][64 * 64];
  __shared__ __attribute__((aligned(16))) unsigned short Vs[2][64][72];
  __shared__ __attribute__((aligned(16))) unsigned short Ss[128][72];
  const int u = blockIdx.x;
  const int v = u & 255;
  const int hi = u >> 8;
  const int sraw = v & 7, g = (v >> 3) & 7;
  const int bn = (v >> 6) + (hi ? 4 : 0);
  const int sblk = hi ? 7 - sraw : sraw;
  const int tid = threadIdx.x, lane = tid & 63, w = tid >> 6;

  const float lg0 = logf(1.f / 32.f), lg1 = logf(1.f / 512.f);
  const float gam = 1.f - expf(lg0 + g * (lg1 - lg0) / 7.f);
  const float l2g = log2f(gam);

  const int s0 = sblk * 128;
  const size_t seqbase = (size_t)bn * 1024;
  const int kc = (lane >> 4) * 8;
  const int ntt = 2 * sblk + 2;

  // per-thread t-column decay factors gamma^(-(tb+r)) (tile-invariant)
  float cf[16];
#pragma unroll
  for (int ti = 0; ti < 4; ++ti)
#pragma unroll
    for (int r = 0; r < 4; ++r)
      cf[ti * 4 + r] = exp2f(l2g * (float)(-(ti * 16 + (lane >> 4) * 4 + r)));
  const int sRow[2] = { w * 32 + (lane & 15), w * 32 + 16 + (lane & 15) };

  // V staging mapping: thread -> 2 rows x 8 cols
  const int t0p = (tid >> 3) * 2;
  const int c0v = (tid & 7) * 8;
  const unsigned short* Vg = Vb + seqbase * 512 + g * 64 + c0v;

#define KSTAGE(t, buf)                                                        \
  {                                                                           \
    gload_chunk(Kb + (seqbase + (t) * 64) * 512 + g * 64, 512, Ks[buf], w * 2 + 0, lane); \
    gload_chunk(Kb + (seqbase + (t) * 64) * 512 + g * 64, 512, Ks[buf], w * 2 + 1, lane); \
  }
#define VLOAD(t, r0, r1)                                                      \
  {                                                                           \
    r0 = *(const bf16x8*)(Vg + (size_t)((t) * 64 + t0p) * 512);               \
    r1 = *(const bf16x8*)(Vg + (size_t)((t) * 64 + t0p + 1) * 512);           \
  }
#define VWRITE(buf, r0, r1)                                                   \
  {                                                                           \
    _Pragma("unroll") for (int j = 0; j < 8; ++j) {                           \
      int d = c0v + j;                                                        \
      ushort2 pp; pp.x = (unsigned short)r0[j]; pp.y = (unsigned short)r1[j]; \
      *(ushort2*)&Vs[buf][d][t0p ^ (d & 0x38)] = pp;                          \
    }                                                                         \
  }

  bf16x8 vA0, vA1, vB0, vB1;

  // prologue: Q(4) + K0(2) + V0(2) = 8 vmem
  const unsigned short* Qg = Qb + (seqbase + s0) * 512 + g * 64;
#pragma unroll
  for (int i = 0; i < 4; ++i) gload_chunk(Qg, 512, Qs, w * 4 + i, lane);
  KSTAGE(0, 0);
  VLOAD(0, vA0, vA1);
  WAITV(0);
  VWRITE(0, vA0, vA1);
  KSTAGE(1, 1);                 // ntt >= 2 always
  VLOAD(1, vB0, vB1);
  LGKM0();
  BAR();

  // hoist Q fragments
  bf16x8 qreg[2][2];
#pragma unroll
  for (int ks = 0; ks < 2; ++ks)
#pragma unroll
    for (int si = 0; si < 2; ++si)
      qreg[ks][si] = frag64(Qs, w * 32 + si * 16 + (lane & 15), ks * 32 + kc);

  f32x4 accY[2][4] = {};

  auto body = [&](int tt, int cur, bf16x8& w0, bf16x8& w1, bf16x8& l0, bf16x8& l1) {
    const int t0 = tt * 64;
    // S^T = mfma(K, Q): D[m=t][n=s]
    f32x4 accSt[4][2] = {};
#pragma unroll
    for (int ks = 0; ks < 2; ++ks) {
      bf16x8 kf[4];
#pragma unroll
      for (int ti = 0; ti < 4; ++ti) kf[ti] = frag64(Ks[cur], ti * 16 + (lane & 15), ks * 32 + kc);
#pragma unroll
      for (int ti = 0; ti < 4; ++ti)
#pragma unroll
        for (int si = 0; si < 2; ++si)
          accSt[ti][si] = MFMA16(kf[ti], qreg[ks][si], accSt[ti][si]);
    }

    // factorized decay: dv = gamma^(s0+s-t0) * gamma^(-(tb+r))
    float rf[2];
    rf[0] = exp2f(l2g * (float)(s0 + sRow[0] - t0));
    rf[1] = exp2f(l2g * (float)(s0 + sRow[1] - t0));
    if (tt >= 2 * sblk) {       // diagonal tiles: need causal mask
#pragma unroll
      for (int ti = 0; ti < 4; ++ti)
#pragma unroll
        for (int si = 0; si < 2; ++si) {
          int tb = ti * 16 + (lane >> 4) * 4;
          ushort4 pk;
#pragma unroll
          for (int r = 0; r < 4; ++r) {
            int diff = (s0 + sRow[si]) - (t0 + tb + r);
            float dv = (diff >= 0) ? rf[si] * cf[ti * 4 + r] : 0.f;
            ((unsigned short*)&pk)[r] = f2bf(accSt[ti][si][r] * dv);
          }
          *(ushort4*)&Ss[sRow[si]][tb] = pk;
        }
    } else {
#pragma unroll
      for (int ti = 0; ti < 4; ++ti)
#pragma unroll
        for (int si = 0; si < 2; ++si) {
          int tb = ti * 16 + (lane >> 4) * 4;
          ushort4 pk;
#pragma unroll
          for (int r = 0; r < 4; ++r)
            ((unsigned short*)&pk)[r] = f2bf(accSt[ti][si][r] * rf[si] * cf[ti * 4 + r]);
          *(ushort4*)&Ss[sRow[si]][tb] = pk;
        }
    }

    // Y += S V   (Ss rows are wave-private: in-order DS pipe, no barrier)
#pragma unroll
    for (int ks = 0; ks < 2; ++ks) {
      bf16x8 af[2], vf[4];
#pragma unroll
      for (int mi = 0; mi < 2; ++mi) af[mi] = *(const bf16x8*)&Ss[sRow[mi]][ks * 32 + kc];
#pragma unroll
      for (int ni = 0; ni < 4; ++ni) {
        int d = ni * 16 + (lane & 15);
        vf[ni] = *(const bf16x8*)&Vs[cur][d][(ks * 32 + kc) ^ (d & 0x38)];
      }
#pragma unroll
      for (int mi = 0; mi < 2; ++mi)
#pragma unroll
        for (int ni = 0; ni < 4; ++ni)
          accY[mi][ni] = MFMA16(af[mi], vf[ni], accY[mi][ni]);
    }

    LGKM0();
    BAR();                       // everyone done reading Ks[cur], Vs[cur]
    if (tt + 1 < ntt) {
      WAITV(0);                  // K(t+1) in LDS, V(t+1) in regs
      VWRITE(cur ^ 1, w0, w1);
      if (tt + 2 < ntt) {        // prefetch t+2 into the buffer just freed
        KSTAGE(tt + 2, cur);
        VLOAD(tt + 2, l0, l1);
      }
      LGKM0();
      BAR();
    }
  };

  for (int tt = 0; tt < ntt; tt += 2) {
    body(tt, 0, vB0, vB1, vA0, vA1);
    body(tt + 1, 1, vA0, vA1, vB0, vB1);
  }

  // groupnorm + gate, write Ab
  float gw[4], gbv[4];
#pragma unroll
  for (int ni = 0; ni < 4; ++ni) {
    int d = ni * 16 + (lane & 15);
    gw[ni] = gnw[g * 64 + d];
    gbv[ni] = gnb[g * 64 + d];
  }
#pragma unroll
  for (int mi = 0; mi < 2; ++mi)
#pragma unroll
    for (int r = 0; r < 4; ++r) {
      float sm = 0.f, sq = 0.f;
#pragma unroll
      for (int ni = 0; ni < 4; ++ni) { float v = accY[mi][ni][r]; sm += v; sq += v * v; }
#pragma unroll
      for (int off = 1; off < 16; off <<= 1) { sm += __shfl_xor(sm, off); sq += __shfl_xor(sq, off); }
      float mean = sm * (1.f / 64.f);
      float var = sq * (1.f / 64.f) - mean * mean;
      float rstd = rsqrtf(var + 1e-5f);
      int row = w * 32 + mi * 16 + (lane >> 4) * 4 + r;
      size_t grow = (seqbase + s0 + row) * 512 + g * 64;
#pragma unroll
      for (int ni = 0; ni < 4; ++ni) {
        int d = ni * 16 + (lane & 15);
        float vv = (accY[mi][ni][r] - mean) * rstd * gw[ni] + gbv[ni];
        float gate = bf2f(Gb[grow + d]);
        Ab[grow + d] = f2bf(vv * gate);
      }
    }
#undef KSTAGE
#undef VLOAD
#undef VWRITE
}

// ---------------- K3: output GEMM ----------------
// tile 128x64, BK=64 double-buffered, 4 waves 2x2; grid (8 colblk, 64 rowblk)

__launch_bounds__(256)
__global__ void k_out(const unsigned short* __restrict__ Ab, const unsigned short* __restrict__ Wt,
                      float* __restrict__ out) {
  __shared__ __attribute__((aligned(16))) unsigned short As[2][128 * 64];
  __shared__ __attribute__((aligned(16))) unsigned short Bs[2][64 * 64];
  const int tid = threadIdx.x, lane = tid & 63, wid = tid >> 6;
  const int wr = wid >> 1, wc = wid & 1;
  const int cb = blockIdx.x, rb = blockIdx.y;

  f32x4 acc[4][2] = {};
  const int kc = (lane >> 4) * 8;
  const unsigned short* Ag = Ab + (size_t)(rb * 128) * 512;
  const unsigned short* Bg = Wt + (size_t)(cb * 64) * 512;

#define OSTAGE(kt, buf)                                                  \
  {                                                                      \
    _Pragma("unroll") for (int i = 0; i < 4; ++i)                        \
        gload_chunk(Ag + (kt) * 64, 512, As[buf], wid * 4 + i, lane);    \
    _Pragma("unroll") for (int i = 0; i < 2; ++i)                        \
        gload_chunk(Bg + (kt) * 64, 512, Bs[buf], wid * 2 + i, lane);    \
  }

  OSTAGE(0, 0);
  for (int kt = 0; kt < 8; ++kt) {
    const int cur = kt & 1;
    if (kt < 7) {
      OSTAGE(kt + 1, cur ^ 1);
      WAITV(6);
    } else {
      WAITV(0);
    }
    BAR();
#pragma unroll
    for (int ks = 0; ks < 2; ++ks) {
      bf16x8 a[4], b[2];
#pragma unroll
      for (int mi = 0; mi < 4; ++mi) a[mi] = frag64(As[cur], wr * 64 + mi * 16 + (lane & 15), ks * 32 + kc);
#pragma unroll
      for (int ni = 0; ni < 2; ++ni) b[ni] = frag64(Bs[cur], wc * 32 + ni * 16 + (lane & 15), ks * 32 + kc);
#pragma unroll
      for (int mi = 0; mi < 4; ++mi)
#pragma unroll
        for (int ni = 0; ni < 2; ++ni)
          acc[mi][ni] = MFMA16(a[mi], b[ni], acc[mi][ni]);
    }
    LGKM0();
    BAR();
  }
#undef OSTAGE

  const int row0 = rb * 128 + wr * 64;
  const int col0 = cb * 64 + wc * 32;
#pragma unroll
  for (int mi = 0; mi < 4; ++mi)
#pragma unroll
    for (int ni = 0; ni < 2; ++ni) {
      int col = col0 + ni * 16 + (lane & 15);
#pragma unroll
      for (int r = 0; r < 4; ++r) {
        int row = row0 + mi * 16 + (lane >> 4) * 4 + r;
        out[(size_t)row * 512 + col] = acc[mi][ni][r];
      }
    }
}

// ---------------- launch ----------------

extern "C" void kernel_launch(void* const* d_in, const int* in_sizes, int n_in,
                              void* d_out, int out_size, void* d_ws, size_t ws_size,
                              hipStream_t stream) {
  const float* X   = (const float*)d_in[0];
  const float* WQ  = (const float*)d_in[1];
  const float* WK  = (const float*)d_in[2];
  const float* WV  = (const float*)d_in[3];
  const float* WG  = (const float*)d_in[4];
  const float* WO  = (const float*)d_in[5];
  const float* gnw = (const float*)d_in[6];
  const float* gnb = (const float*)d_in[7];
  float* out = (float*)d_out;

  char* ws = (char*)d_ws;
  const size_t SZ_BUF = (size_t)8192 * 512 * 2;   // 8 MB bf16
  unsigned short* Xb   = (unsigned short*)(ws);
  unsigned short* Qb   = (unsigned short*)(ws + SZ_BUF);
  unsigned short* Kb   = (unsigned short*)(ws + 2 * SZ_BUF);
  unsigned short* Vb   = (unsigned short*)(ws + 3 * SZ_BUF);
  unsigned short* Gb   = (unsigned short*)(ws + 4 * SZ_BUF);
  unsigned short* Ab   = (unsigned short*)(ws + 5 * SZ_BUF);
  unsigned short* Wcat = (unsigned short*)(ws + 6 * SZ_BUF);            // 2 MB
  unsigned short* WoT  = (unsigned short*)(ws + 6 * SZ_BUF + 2097152);  // 0.5 MB
  float2* qtab = (float2*)(ws + 6 * SZ_BUF + 2097152 + 524288);         // 256 KB
  float2* ktab = qtab + 32768;                                          // 256 KB

  k_prep<<<9344, 256, 0, stream>>>(X, WQ, WK, WV, WG, WO, Xb, Wcat, WoT, qtab, ktab);
  k_proj<<<dim3(8, 32), 512, 0, stream>>>(Xb, Wcat, qtab, ktab, Qb, Kb, Vb, Gb);
  k_ret<<<512, 256, 0, stream>>>(Qb, Kb, Vb, Gb, gnw, gnb, Ab);
  k_out<<<dim3(8, 64), 256, 0, stream>>>(Ab, WoT, out);
}

// Round 5
// 149.801 us; speedup vs baseline: 1.4891x; 1.0553x over previous
//
#include <hip/hip_runtime.h>
#include <hip/hip_bf16.h>
#include <math.h>

// MultiScaleRetention: B=2,N=4,S=1024,H=512, HEADS=8, HEAD=64
//  k_prep: X->bf16, LDS-transposed WcatT/WoT, f32 xpos tables (one launch)
//  k_proj: proj GEMM 256x256 tile, 8 waves 2x4, dbuf BK=64, counted vmcnt;
//          LDS-transpose epilogue (vectorized stores, in-register rot2)
//  k_ret : retention + factorized decay (cvt_pk pack) + groupnorm + gate -> Ab
//  k_out : out GEMM 128x64 tile -> fp32
// Raw s_barrier + counted vmcnt in MFMA loops (T3/T4).

typedef __attribute__((ext_vector_type(8))) short bf16x8;
typedef __attribute__((ext_vector_type(4))) float f32x4;

#define MFMA16(a, b, c) __builtin_amdgcn_mfma_f32_16x16x32_bf16(a, b, c, 0, 0, 0)
#define BAR() __builtin_amdgcn_s_barrier()
#define WAITV(n) asm volatile("s_waitcnt vmcnt(" #n ")" ::: "memory")
#define LGKM0() asm volatile("s_waitcnt lgkmcnt(0)" ::: "memory")
// packed f32->bf16 RTNE: D.lo = bf16(a), D.hi = bf16(b)
#define CVTPK(a, b) ({ unsigned _r;                                   \
  asm("v_cvt_pk_bf16_f32 %0, %1, %2" : "=v"(_r) : "v"(a), "v"(b));    \
  _r; })

__device__ __forceinline__ unsigned short f2bf(float f) {
  union { float f; unsigned u; } x; x.f = f;
  unsigned r = x.u + 0x7FFFu + ((x.u >> 16) & 1u);
  return (unsigned short)(r >> 16);
}
__device__ __forceinline__ float bf2f(unsigned short b) {
  union { unsigned u; float f; } x; x.u = ((unsigned)b) << 16;
  return x.f;
}

// 1KB chunk = 8 rows x 128B of a [R][64]-bf16 LDS tile. LDS dest linear
// (gload_lds requirement); global source column pre-swizzled so reads use
// byte ^ ((row&7)<<4) conflict-free.
__device__ __forceinline__ void gload_chunk(const unsigned short* gtile, size_t gstride,
                                            unsigned short* lds, int chunk, int lane) {
  int r = (chunk << 3) + (lane >> 3);
  int colel = ((lane & 7) ^ (lane >> 3)) << 3;
  const unsigned short* gp = gtile + (size_t)r * gstride + colel;
  __builtin_amdgcn_global_load_lds(
      (const __attribute__((address_space(1))) unsigned int*)gp,
      (__attribute__((address_space(3))) unsigned int*)((char*)lds + (chunk << 10)),
      16, 0, 0);
}

__device__ __forceinline__ bf16x8 frag64(const unsigned short* lds, int row, int colel) {
  return *(const bf16x8*)((const char*)lds + row * 128 + ((colel * 2) ^ ((row & 7) << 4)));
}

// ---------------- merged prep ----------------
// [0,4096): X->bf16 ; [4096,4288): WQ/WK/WV transpose ; [4288,4352): WG ;
// [4352,4416): WO ; [4416,4544): f32 tables

__global__ void k_prep(const float* __restrict__ X, const float* __restrict__ WQ,
                       const float* __restrict__ WK, const float* __restrict__ WV,
                       const float* __restrict__ WG, const float* __restrict__ WO,
                       unsigned short* __restrict__ Xb, unsigned short* __restrict__ Wcat,
                       unsigned short* __restrict__ WoT,
                       float2* __restrict__ qtab, float2* __restrict__ ktab) {
  int b = blockIdx.x, tid = threadIdx.x;
  if (b < 4096) {
    int idx = b * 256 + tid;
    float4 v = ((const float4*)X)[idx];
    uint2 o;
    o.x = CVTPK(v.x, v.y);
    o.y = CVTPK(v.z, v.w);
    ((uint2*)Xb)[idx] = o;
    return;
  }
  if (b < 4416) {
    // 64x64 LDS-transpose tiles: coalesced reads + coalesced writes
    __shared__ float Ls[64][68];
    const float* src;
    unsigned short* dst;
    size_t src_ld, dst_rowbase, dst_colbase;
    int b2;
    if (b < 4288) {            // WQ/WK/WV: src W[g][k][d] (ld 64) -> Wcat row g*64+d
      b2 = b - 4096;
      const float* W = (b2 < 64) ? WQ : (b2 < 128 ? WK : WV);
      int cls = (b2 < 64) ? 0 : (b2 < 128 ? 1 : 2);
      int gg = (b2 & 63) >> 3, kt = b2 & 7;
      src = W + ((size_t)gg * 512 + kt * 64) * 64;   // rows k, cols d, ld 64
      src_ld = 64;
      dst = Wcat;
      dst_rowbase = (size_t)cls * 512 + gg * 64;     // + d
      dst_colbase = (size_t)kt * 64;                 // + k
    } else if (b < 4352) {     // WG: src WG[k][n'] (ld 512) -> Wcat row 1536+n'
      b2 = b - 4288;
      int kt = b2 >> 3, nt = b2 & 7;
      src = WG + (size_t)(kt * 64) * 512 + nt * 64;
      src_ld = 512;
      dst = Wcat;
      dst_rowbase = 1536 + (size_t)nt * 64;
      dst_colbase = (size_t)kt * 64;
    } else {                   // WO: src WO[k][n] (ld 512) -> WoT row n
      b2 = b - 4352;
      int kt = b2 >> 3, nt = b2 & 7;
      src = WO + (size_t)(kt * 64) * 512 + nt * 64;
      src_ld = 512;
      dst = WoT;
      dst_rowbase = (size_t)nt * 64;
      dst_colbase = (size_t)kt * 64;
    }
#pragma unroll
    for (int i = 0; i < 4; ++i) {         // 64x64 f32 = 1024 float4
      int e = i * 256 + tid;
      int r = e >> 4, c4 = e & 15;
      float4 v = *(const float4*)(src + (size_t)r * src_ld + c4 * 4);
      *(float4*)&Ls[r][c4 * 4] = v;
    }
    __syncthreads();
    int d = tid >> 2, kp = (tid & 3) * 16;
    unsigned short tmp[16];
#pragma unroll
    for (int k = 0; k < 16; ++k) tmp[k] = f2bf(Ls[kp + k][d]);
    size_t orow = (dst_rowbase + d) * 512 + dst_colbase + kp;
    *(bf16x8*)(dst + orow) = *(bf16x8*)&tmp[0];
    *(bf16x8*)(dst + orow + 8) = *(bf16x8*)&tmp[8];
    return;
  }
  {                            // tables, f32 math
    int idx = (b - 4416) * 256 + tid;     // s*32 + i
    int s = idx >> 5, i = idx & 31;
    float invf = exp2f(-(float)i * (13.2877123795f / 32.0f));  // 10000^(-i/32)
    float ang = (float)s * invf;
    float sn = sinf(ang), cs = cosf(ang);
    float sv = (2.f * i + 25.6f) / 89.6f;
    float sc = exp2f(log2f(sv) * (float)s * (1.f / 512.f));
    qtab[idx] = make_float2(cs * sc, sn * sc);
    ktab[idx] = make_float2(cs / sc, sn / sc);
  }
}

// ---------------- K1: projection GEMM + xpos/silu epilogue ----------------
// tile 256x256, BK=64 double-buffered, 8 waves 2x4 (per-wave 128x64);
// grid (8 colblk, 32 rowblk) = 256 blocks = 1/CU, LDS 128KB

__launch_bounds__(512, 2)
__global__ void k_proj(const unsigned short* __restrict__ Xb, const unsigned short* __restrict__ Wt,
                       const float2* __restrict__ qtab, const float2* __restrict__ ktab,
                       unsigned short* __restrict__ Qb, unsigned short* __restrict__ Kb,
                       unsigned short* __restrict__ Vb, unsigned short* __restrict__ Gb) {
  __shared__ __attribute__((aligned(16))) unsigned short As[2][256 * 64];
  __shared__ __attribute__((aligned(16))) unsigned short Bs[2][256 * 64];
  const int tid = threadIdx.x, lane = tid & 63, wid = tid >> 6;
  const int wr = wid >> 2, wc = wid & 3;     // 2 x 4 waves
  const int cb = blockIdx.x, rb = blockIdx.y;

  f32x4 acc[8][4] = {};
  const int kc = (lane >> 4) * 8;
  const unsigned short* Ag = Xb + (size_t)(rb * 256) * 512;
  const unsigned short* Bg = Wt + (size_t)(cb * 256) * 512;

#define PSTAGE(kt, buf)                                             \
  {                                                                 \
    _Pragma("unroll") for (int i = 0; i < 4; ++i) {                 \
      gload_chunk(Ag + (kt) * 64, 512, As[buf], wid * 4 + i, lane); \
      gload_chunk(Bg + (kt) * 64, 512, Bs[buf], wid * 4 + i, lane); \
    }                                                               \
  }

  PSTAGE(0, 0);
  for (int kt = 0; kt < 8; ++kt) {
    const int cur = kt & 1;
    if (kt < 7) {
      PSTAGE(kt + 1, cur ^ 1);
      WAITV(8);                 // own 8 loads of tile kt done; 8 of kt+1 in flight
    } else {
      WAITV(0);
    }
    BAR();
#pragma unroll
    for (int ks = 0; ks < 2; ++ks) {
      bf16x8 a[8], b[4];
#pragma unroll
      for (int mi = 0; mi < 8; ++mi) a[mi] = frag64(As[cur], wr * 128 + mi * 16 + (lane & 15), ks * 32 + kc);
#pragma unroll
      for (int ni = 0; ni < 4; ++ni) b[ni] = frag64(Bs[cur], wc * 64 + ni * 16 + (lane & 15), ks * 32 + kc);
#pragma unroll
      for (int mi = 0; mi < 8; ++mi)
#pragma unroll
        for (int ni = 0; ni < 4; ++ni)
          acc[mi][ni] = MFMA16(a[mi], b[ni], acc[mi][ni]);
    }
    LGKM0();                    // all ds_reads of this tile complete
    BAR();                      // safe for next iter to overwrite other buffer
  }
#undef PSTAGE

  // ---- epilogue: per-wave LDS transpose -> vectorized stores ----
  // patch [16 rows][68 cols] f32 per wave (4.25KB x 8 = 34KB, reuses As)
  float* patch = (float*)As + wid * (16 * 68);
  const int rr = lane >> 2;            // reader row 0..15
  const int c0 = (lane & 3) * 16;      // reader col base
  const int row0 = rb * 256 + wr * 128;
  const int colc = (cb & 1) * 256 + wc * 64;  // col within class (0..511)
  const int cls = cb >> 1;             // 0=Q 1=K 2=V 3=gate
  const int i0 = c0 >> 1;

#pragma unroll
  for (int mi = 0; mi < 8; ++mi) {
#pragma unroll
    for (int ni = 0; ni < 4; ++ni)
#pragma unroll
      for (int r = 0; r < 4; ++r)
        patch[((lane >> 4) * 4 + r) * 68 + ni * 16 + (lane & 15)] = acc[mi][ni][r];
    // wave-private patch; compiler inserts lgkmcnt for RAW
    float v[16];
#pragma unroll
    for (int q = 0; q < 4; ++q) {
      float4 t = *(float4*)&patch[rr * 68 + c0 + q * 4];
      v[q * 4 + 0] = t.x; v[q * 4 + 1] = t.y; v[q * 4 + 2] = t.z; v[q * 4 + 3] = t.w;
    }
    int grow = row0 + mi * 16 + rr;
    int s = grow & 1023;
    unsigned out[8];
    if (cls <= 1) {
      const float2* tab = (cls == 0) ? qtab : ktab;
#pragma unroll
      for (int p = 0; p < 8; ++p) {
        float2 t = tab[s * 32 + i0 + p];
        float e = v[2 * p], o = v[2 * p + 1];
        out[p] = CVTPK(e * t.x - o * t.y, o * t.x + e * t.y);
      }
    } else if (cls == 2) {
#pragma unroll
      for (int p = 0; p < 8; ++p) out[p] = CVTPK(v[2 * p], v[2 * p + 1]);
    } else {
#pragma unroll
      for (int p = 0; p < 8; ++p) {
        float e = v[2 * p], o = v[2 * p + 1];
        e = e / (1.f + __expf(-e));
        o = o / (1.f + __expf(-o));
        out[p] = CVTPK(e, o);
      }
    }
    unsigned short* dst = (cls == 0) ? Qb : (cls == 1) ? Kb : (cls == 2) ? Vb : Gb;
    *(uint4*)(dst + (size_t)grow * 512 + colc + c0) = *(uint4*)&out[0];
    *(uint4*)(dst + (size_t)grow * 512 + colc + c0 + 8) = *(uint4*)&out[4];
  }
}

// ---------------- K2: retention + decay + groupnorm + gate ----------------
// flat grid 512; CU-pair balancing: blocks u and u+256 get sblk f and 7-f

__launch_bounds__(256)
__global__ void k_ret(const unsigned short* __restrict__ Qb, const unsigned short* __restrict__ Kb,
                      const unsigned short* __restrict__ Vb, const unsigned short* __restrict__ Gb,
                      const float* __restrict__ gnw, const float* __restrict__ gnb,
                      unsigned short* __restrict__ Ab) {
  __shared__ __attribute__((aligned(16))) unsigned short Qs[128 * 64];
  __shared__ __attribute__((aligned(16))) unsigned short Ks[2][64 * 64];
  __shared__ __attribute__((aligned(16))) unsigned short Vs[2][64][72];
  __shared__ __attribute__((aligned(16))) unsigned short Ss[128][72];
  const int u = blockIdx.x;
  const int v = u & 255;
  const int hi = u >> 8;
  const int sraw = v & 7, g = (v >> 3) & 7;
  const int bn = (v >> 6) + (hi ? 4 : 0);
  const int sblk = hi ? 7 - sraw : sraw;
  const int tid = threadIdx.x, lane = tid & 63, w = tid >> 6;

  const float lg0 = logf(1.f / 32.f), lg1 = logf(1.f / 512.f);
  const float gam = 1.f - expf(lg0 + g * (lg1 - lg0) / 7.f);
  const float l2g = log2f(gam);

  const int s0 = sblk * 128;
  const size_t seqbase = (size_t)bn * 1024;
  const int kc = (lane >> 4) * 8;
  const int ntt = 2 * sblk + 2;

  // per-thread t-column decay factors gamma^(-(tb+r)) (tile-invariant)
  float cf[16];
#pragma unroll
  for (int ti = 0; ti < 4; ++ti)
#pragma unroll
    for (int r = 0; r < 4; ++r)
      cf[ti * 4 + r] = exp2f(l2g * (float)(-(ti * 16 + (lane >> 4) * 4 + r)));
  const int sRow[2] = { w * 32 + (lane & 15), w * 32 + 16 + (lane & 15) };

  // V staging mapping: thread -> 2 rows x 8 cols
  const int t0p = (tid >> 3) * 2;
  const int c0v = (tid & 7) * 8;
  const unsigned short* Vg = Vb + seqbase * 512 + g * 64 + c0v;

#define KSTAGE(t, buf)                                                        \
  {                                                                           \
    gload_chunk(Kb + (seqbase + (t) * 64) * 512 + g * 64, 512, Ks[buf], w * 2 + 0, lane); \
    gload_chunk(Kb + (seqbase + (t) * 64) * 512 + g * 64, 512, Ks[buf], w * 2 + 1, lane); \
  }
#define VLOAD(t, r0, r1)                                                      \
  {                                                                           \
    r0 = *(const bf16x8*)(Vg + (size_t)((t) * 64 + t0p) * 512);               \
    r1 = *(const bf16x8*)(Vg + (size_t)((t) * 64 + t0p + 1) * 512);           \
  }
#define VWRITE(buf, r0, r1)                                                   \
  {                                                                           \
    _Pragma("unroll") for (int j = 0; j < 8; ++j) {                           \
      int d = c0v + j;                                                        \
      ushort2 pp; pp.x = (unsigned short)r0[j]; pp.y = (unsigned short)r1[j]; \
      *(ushort2*)&Vs[buf][d][t0p ^ (d & 0x38)] = pp;                          \
    }                                                                         \
  }

  bf16x8 vA0, vA1, vB0, vB1;

  // prologue: Q(4) + K0(2) + V0(2) = 8 vmem
  const unsigned short* Qg = Qb + (seqbase + s0) * 512 + g * 64;
#pragma unroll
  for (int i = 0; i < 4; ++i) gload_chunk(Qg, 512, Qs, w * 4 + i, lane);
  KSTAGE(0, 0);
  VLOAD(0, vA0, vA1);
  WAITV(0);
  VWRITE(0, vA0, vA1);
  KSTAGE(1, 1);                 // ntt >= 2 always
  VLOAD(1, vB0, vB1);
  LGKM0();
  BAR();

  // hoist Q fragments
  bf16x8 qreg[2][2];
#pragma unroll
  for (int ks = 0; ks < 2; ++ks)
#pragma unroll
    for (int si = 0; si < 2; ++si)
      qreg[ks][si] = frag64(Qs, w * 32 + si * 16 + (lane & 15), ks * 32 + kc);

  f32x4 accY[2][4] = {};

  auto body = [&](int tt, int cur, bf16x8& w0, bf16x8& w1, bf16x8& l0, bf16x8& l1) {
    const int t0 = tt * 64;
    // S^T = mfma(K, Q): D[m=t][n=s]
    f32x4 accSt[4][2] = {};
#pragma unroll
    for (int ks = 0; ks < 2; ++ks) {
      bf16x8 kf[4];
#pragma unroll
      for (int ti = 0; ti < 4; ++ti) kf[ti] = frag64(Ks[cur], ti * 16 + (lane & 15), ks * 32 + kc);
#pragma unroll
      for (int ti = 0; ti < 4; ++ti)
#pragma unroll
        for (int si = 0; si < 2; ++si)
          accSt[ti][si] = MFMA16(kf[ti], qreg[ks][si], accSt[ti][si]);
    }

    // factorized decay: dv = gamma^(s0+s-t0) * gamma^(-(tb+r)); cvt_pk pack
    float rf[2];
    rf[0] = exp2f(l2g * (float)(s0 + sRow[0] - t0));
    rf[1] = exp2f(l2g * (float)(s0 + sRow[1] - t0));
    if (tt >= 2 * sblk) {       // diagonal tiles: need causal mask
#pragma unroll
      for (int ti = 0; ti < 4; ++ti)
#pragma unroll
        for (int si = 0; si < 2; ++si) {
          int tb = ti * 16 + (lane >> 4) * 4;
          float p[4];
#pragma unroll
          for (int r = 0; r < 4; ++r) {
            int diff = (s0 + sRow[si]) - (t0 + tb + r);
            float dv = (diff >= 0) ? rf[si] * cf[ti * 4 + r] : 0.f;
            p[r] = accSt[ti][si][r] * dv;
          }
          uint2 pk; pk.x = CVTPK(p[0], p[1]); pk.y = CVTPK(p[2], p[3]);
          *(uint2*)&Ss[sRow[si]][tb] = pk;
        }
    } else {
#pragma unroll
      for (int ti = 0; ti < 4; ++ti)
#pragma unroll
        for (int si = 0; si < 2; ++si) {
          int tb = ti * 16 + (lane >> 4) * 4;
          uint2 pk;
          pk.x = CVTPK(accSt[ti][si][0] * rf[si] * cf[ti * 4 + 0],
                       accSt[ti][si][1] * rf[si] * cf[ti * 4 + 1]);
          pk.y = CVTPK(accSt[ti][si][2] * rf[si] * cf[ti * 4 + 2],
                       accSt[ti][si][3] * rf[si] * cf[ti * 4 + 3]);
          *(uint2*)&Ss[sRow[si]][tb] = pk;
        }
    }

    // Y += S V   (Ss rows are wave-private: in-order DS pipe, no barrier)
#pragma unroll
    for (int ks = 0; ks < 2; ++ks) {
      bf16x8 af[2], vf[4];
#pragma unroll
      for (int mi = 0; mi < 2; ++mi) af[mi] = *(const bf16x8*)&Ss[sRow[mi]][ks * 32 + kc];
#pragma unroll
      for (int ni = 0; ni < 4; ++ni) {
        int d = ni * 16 + (lane & 15);
        vf[ni] = *(const bf16x8*)&Vs[cur][d][(ks * 32 + kc) ^ (d & 0x38)];
      }
#pragma unroll
      for (int mi = 0; mi < 2; ++mi)
#pragma unroll
        for (int ni = 0; ni < 4; ++ni)
          accY[mi][ni] = MFMA16(af[mi], vf[ni], accY[mi][ni]);
    }

    LGKM0();
    BAR();                       // everyone done reading Ks[cur], Vs[cur]
    if (tt + 1 < ntt) {
      WAITV(0);                  // K(t+1) in LDS, V(t+1) in regs
      VWRITE(cur ^ 1, w0, w1);
      if (tt + 2 < ntt) {        // prefetch t+2 into the buffer just freed
        KSTAGE(tt + 2, cur);
        VLOAD(tt + 2, l0, l1);
      }
      LGKM0();
      BAR();
    }
  };

  for (int tt = 0; tt < ntt; tt += 2) {
    body(tt, 0, vB0, vB1, vA0, vA1);
    body(tt + 1, 1, vA0, vA1, vB0, vB1);
  }

  // groupnorm + gate, write Ab
  float gw[4], gbv[4];
#pragma unroll
  for (int ni = 0; ni < 4; ++ni) {
    int d = ni * 16 + (lane & 15);
    gw[ni] = gnw[g * 64 + d];
    gbv[ni] = gnb[g * 64 + d];
  }
#pragma unroll
  for (int mi = 0; mi < 2; ++mi)
#pragma unroll
    for (int r = 0; r < 4; ++r) {
      float sm = 0.f, sq = 0.f;
#pragma unroll
      for (int ni = 0; ni < 4; ++ni) { float vv = accY[mi][ni][r]; sm += vv; sq += vv * vv; }
#pragma unroll
      for (int off = 1; off < 16; off <<= 1) { sm += __shfl_xor(sm, off); sq += __shfl_xor(sq, off); }
      float mean = sm * (1.f / 64.f);
      float var = sq * (1.f / 64.f) - mean * mean;
      float rstd = rsqrtf(var + 1e-5f);
      int row = w * 32 + mi * 16 + (lane >> 4) * 4 + r;
      size_t grow = (seqbase + s0 + row) * 512 + g * 64;
#pragma unroll
      for (int ni = 0; ni < 4; ++ni) {
        int d = ni * 16 + (lane & 15);
        float vv = (accY[mi][ni][r] - mean) * rstd * gw[ni] + gbv[ni];
        float gate = bf2f(Gb[grow + d]);
        Ab[grow + d] = f2bf(vv * gate);
      }
    }
#undef KSTAGE
#undef VLOAD
#undef VWRITE
}

// ---------------- K3: output GEMM ----------------
// tile 128x64, BK=64 double-buffered, 4 waves 2x2; grid (8 colblk, 64 rowblk)

__launch_bounds__(256)
__global__ void k_out(const unsigned short* __restrict__ Ab, const unsigned short* __restrict__ Wt,
                      float* __restrict__ out) {
  __shared__ __attribute__((aligned(16))) unsigned short As[2][128 * 64];
  __shared__ __attribute__((aligned(16))) unsigned short Bs[2][64 * 64];
  const int tid = threadIdx.x, lane = tid & 63, wid = tid >> 6;
  const int wr = wid >> 1, wc = wid & 1;
  const int cb = blockIdx.x, rb = blockIdx.y;

  f32x4 acc[4][2] = {};
  const int kc = (lane >> 4) * 8;
  const unsigned short* Ag = Ab + (size_t)(rb * 128) * 512;
  const unsigned short* Bg = Wt + (size_t)(cb * 64) * 512;

#define OSTAGE(kt, buf)                                                  \
  {                                                                      \
    _Pragma("unroll") for (int i = 0; i < 4; ++i)                        \
        gload_chunk(Ag + (kt) * 64, 512, As[buf], wid * 4 + i, lane);    \
    _Pragma("unroll") for (int i = 0; i < 2; ++i)                        \
        gload_chunk(Bg + (kt) * 64, 512, Bs[buf], wid * 2 + i, lane);    \
  }

  OSTAGE(0, 0);
  for (int kt = 0; kt < 8; ++kt) {
    const int cur = kt & 1;
    if (kt < 7) {
      OSTAGE(kt + 1, cur ^ 1);
      WAITV(6);
    } else {
      WAITV(0);
    }
    BAR();
#pragma unroll
    for (int ks = 0; ks < 2; ++ks) {
      bf16x8 a[4], b[2];
#pragma unroll
      for (int mi = 0; mi < 4; ++mi) a[mi] = frag64(As[cur], wr * 64 + mi * 16 + (lane & 15), ks * 32 + kc);
#pragma unroll
      for (int ni = 0; ni < 2; ++ni) b[ni] = frag64(Bs[cur], wc * 32 + ni * 16 + (lane & 15), ks * 32 + kc);
#pragma unroll
      for (int mi = 0; mi < 4; ++mi)
#pragma unroll
        for (int ni = 0; ni < 2; ++ni)
          acc[mi][ni] = MFMA16(a[mi], b[ni], acc[mi][ni]);
    }
    LGKM0();
    BAR();
  }
#undef OSTAGE

  const int row0 = rb * 128 + wr * 64;
  const int col0 = cb * 64 + wc * 32;
#pragma unroll
  for (int mi = 0; mi < 4; ++mi)
#pragma unroll
    for (int ni = 0; ni < 2; ++ni) {
      int col = col0 + ni * 16 + (lane & 15);
#pragma unroll
      for (int r = 0; r < 4; ++r) {
        int row = row0 + mi * 16 + (lane >> 4) * 4 + r;
        out[(size_t)row * 512 + col] = acc[mi][ni][r];
      }
    }
}

// ---------------- launch ----------------

extern "C" void kernel_launch(void* const* d_in, const int* in_sizes, int n_in,
                              void* d_out, int out_size, void* d_ws, size_t ws_size,
                              hipStream_t stream) {
  const float* X   = (const float*)d_in[0];
  const float* WQ  = (const float*)d_in[1];
  const float* WK  = (const float*)d_in[2];
  const float* WV  = (const float*)d_in[3];
  const float* WG  = (const float*)d_in[4];
  const float* WO  = (const float*)d_in[5];
  const float* gnw = (const float*)d_in[6];
  const float* gnb = (const float*)d_in[7];
  float* out = (float*)d_out;

  char* ws = (char*)d_ws;
  const size_t SZ_BUF = (size_t)8192 * 512 * 2;   // 8 MB bf16
  unsigned short* Xb   = (unsigned short*)(ws);
  unsigned short* Qb   = (unsigned short*)(ws + SZ_BUF);
  unsigned short* Kb   = (unsigned short*)(ws + 2 * SZ_BUF);
  unsigned short* Vb   = (unsigned short*)(ws + 3 * SZ_BUF);
  unsigned short* Gb   = (unsigned short*)(ws + 4 * SZ_BUF);
  unsigned short* Ab   = (unsigned short*)(ws + 5 * SZ_BUF);
  unsigned short* Wcat = (unsigned short*)(ws + 6 * SZ_BUF);            // 2 MB
  unsigned short* WoT  = (unsigned short*)(ws + 6 * SZ_BUF + 2097152);  // 0.5 MB
  float2* qtab = (float2*)(ws + 6 * SZ_BUF + 2097152 + 524288);         // 256 KB
  float2* ktab = qtab + 32768;                                          // 256 KB

  k_prep<<<4544, 256, 0, stream>>>(X, WQ, WK, WV, WG, WO, Xb, Wcat, WoT, qtab, ktab);
  k_proj<<<dim3(8, 32), 512, 0, stream>>>(Xb, Wcat, qtab, ktab, Qb, Kb, Vb, Gb);
  k_ret<<<512, 256, 0, stream>>>(Qb, Kb, Vb, Gb, gnw, gnb, Ab);
  k_out<<<dim3(8, 64), 256, 0, stream>>>(Ab, WoT, out);
}